// Round 1
// baseline (5291.014 us; speedup 1.0000x reference)
//
#include <hip/hip_runtime.h>
#include <math.h>

#define BB   256
#define LL   100
#define CIN  38
#define COUT 38
#define DD   512
#define HH   8
#define EE   3
#define DFF  512
#define DHD  64
#define NTOK (BB*LL)   // 25600

// ---------------------------------------------------------------- PE table
__global__ __launch_bounds__(256) void pe_kernel(float* __restrict__ pe) {
    int idx = blockIdx.x * 256 + threadIdx.x;
    if (idx >= LL * DD) return;
    int l = idx / DD, d = idx % DD;
    // div[i] = exp(2i * (-ln(10000)/D)),  d = 2i or 2i+1
    float e = (float)(d & ~1) * (-9.210340371976184f / (float)DD);
    float ang = (float)l * expf(e);
    pe[idx] = (d & 1) ? cosf(ang) : sinf(ang);
}

// ------------------------------------------------- mask -> additive bias
__global__ void expand_mask_kernel(const unsigned char* __restrict__ mraw,
                                   float* __restrict__ mb) {
    int i = blockIdx.x * 256 + threadIdx.x;
    if (i >= LL * LL) return;
    // mask[0][0] and mask[0][1] are always True (|i-j|<=5 band) -> sniff layout
    unsigned char b0 = mraw[0], b1 = mraw[1], b2 = mraw[2], b3 = mraw[3];
    bool v;
    if (b0 == 1 && b1 == 1)                      v = mraw[i] != 0;                          // u8 / bool
    else if (b0 == 1 && b1 == 0 && b2 == 0 && b3 == 0)
                                                 v = ((const int*)mraw)[i] != 0;            // int32
    else if (b0 == 0x80 && b1 == 0x3F)           v = ((const unsigned short*)mraw)[i] != 0; // bf16 1.0
    else if (b0 == 0 && b1 == 0x3C)              v = ((const unsigned short*)mraw)[i] != 0; // f16 1.0
    else if (b0 == 0 && b1 == 0 && b2 == 0x80 && b3 == 0x3F)
                                                 v = ((const float*)mraw)[i] != 0.f;        // f32 1.0
    else                                         v = mraw[i] != 0;
    mb[i] = v ? 0.f : -1.0e30f;
}

// ---------------------------------------------------------------- embed
// h[n][d] = sum_{c,t} x[circ(l,t)][c] * ew[d][c][t] + pe[l][d]
__global__ __launch_bounds__(256) void embed_kernel(const float* __restrict__ x,
                                                    const float* __restrict__ ew,
                                                    const float* __restrict__ pe,
                                                    float* __restrict__ h) {
    __shared__ float xw[8][114];
    __shared__ int   ls[8];
    int tid = threadIdx.x;
    int n0  = blockIdx.x * 8;
    if (tid < 8) ls[tid] = (n0 + tid) % LL;
    for (int idx = tid; idx < 8 * 114; idx += 256) {
        int tk = idx / 114, p = idx % 114;
        int slot = p / 38, c = p % 38;
        int n = n0 + tk; int b = n / LL, l = n % LL;
        int lsrc = (slot == 0) ? (l + LL - 1) % LL : (slot == 1) ? l : (l + 1) % LL;
        xw[tk][slot * 38 + c] = x[(size_t)(b * LL + lsrc) * CIN + c];
    }
    __syncthreads();
    for (int d = tid; d < DD; d += 256) {
        const float* w = ew + (size_t)d * 114;   // [d][c][t] contiguous 114
        float acc[8] = {0.f,0.f,0.f,0.f,0.f,0.f,0.f,0.f};
        for (int c = 0; c < 38; ++c) {
            float w0 = w[c*3+0], w1 = w[c*3+1], w2 = w[c*3+2];
            #pragma unroll
            for (int tk = 0; tk < 8; ++tk)
                acc[tk] += xw[tk][c]*w0 + xw[tk][38+c]*w1 + xw[tk][76+c]*w2;
        }
        #pragma unroll
        for (int tk = 0; tk < 8; ++tk)
            h[(size_t)(n0 + tk) * DD + d] = acc[tk] + pe[ls[tk] * DD + d];
    }
}

// ------------------------------------------------- C[M,N] = A[M,K] @ W[N,K]^T + bias  (EPI=1: exact GELU)
template<int EPI>
__global__ __launch_bounds__(256) void gemm_xwT(const float* __restrict__ A,
                                                const float* __restrict__ W,
                                                const float* __restrict__ bias,
                                                float* __restrict__ C,
                                                int M, int N, int K) {
    __shared__ float As[16][68];   // [k][m], pitch 68 floats (16B-aligned rows, bank-spread)
    __shared__ float Ws[16][68];   // [k][n]
    const int tid = threadIdx.x;
    const int row = tid >> 2;           // 0..63
    const int kc  = (tid & 3) << 2;     // 0,4,8,12
    const int bn = blockIdx.x, bm = blockIdx.y;
    const float* Ap = A + (size_t)(bm * 64 + row) * K + kc;
    const float* Wp = W + (size_t)(bn * 64 + row) * K + kc;
    const int ty = tid >> 4, tx = tid & 15;
    float acc[4][4] = {};
    for (int k0 = 0; k0 < K; k0 += 16) {
        float4 a4 = *(const float4*)(Ap + k0);
        float4 w4 = *(const float4*)(Wp + k0);
        __syncthreads();
        As[kc+0][row] = a4.x; As[kc+1][row] = a4.y; As[kc+2][row] = a4.z; As[kc+3][row] = a4.w;
        Ws[kc+0][row] = w4.x; Ws[kc+1][row] = w4.y; Ws[kc+2][row] = w4.z; Ws[kc+3][row] = w4.w;
        __syncthreads();
        #pragma unroll
        for (int kk = 0; kk < 16; ++kk) {
            const float4 av = *(const float4*)&As[kk][ty << 2];
            const float4 wv = *(const float4*)&Ws[kk][tx << 2];
            acc[0][0] += av.x*wv.x; acc[0][1] += av.x*wv.y; acc[0][2] += av.x*wv.z; acc[0][3] += av.x*wv.w;
            acc[1][0] += av.y*wv.x; acc[1][1] += av.y*wv.y; acc[1][2] += av.y*wv.z; acc[1][3] += av.y*wv.w;
            acc[2][0] += av.z*wv.x; acc[2][1] += av.z*wv.y; acc[2][2] += av.z*wv.z; acc[2][3] += av.z*wv.w;
            acc[3][0] += av.w*wv.x; acc[3][1] += av.w*wv.y; acc[3][2] += av.w*wv.z; acc[3][3] += av.w*wv.w;
        }
    }
    const int cn = bn * 64 + (tx << 2);
    float4 bv = *(const float4*)(bias + cn);
    #pragma unroll
    for (int i = 0; i < 4; ++i) {
        int cm = bm * 64 + (ty << 2) + i;
        float4 o;
        o.x = acc[i][0] + bv.x; o.y = acc[i][1] + bv.y;
        o.z = acc[i][2] + bv.z; o.w = acc[i][3] + bv.w;
        if (EPI == 1) {
            o.x = 0.5f * o.x * (1.f + erff(o.x * 0.70710678118654752f));
            o.y = 0.5f * o.y * (1.f + erff(o.y * 0.70710678118654752f));
            o.z = 0.5f * o.z * (1.f + erff(o.z * 0.70710678118654752f));
            o.w = 0.5f * o.w * (1.f + erff(o.w * 0.70710678118654752f));
        }
        *(float4*)(C + (size_t)cm * N + cn) = o;
    }
}

// ------------------------------------------------- attention, one (b,h) per block
// reads q,k,v (layout [n][D], head-slice columns); writes output IN PLACE into qbuf slice.
__global__ __launch_bounds__(256) void attn_kernel(float* __restrict__ qbuf,
                                                   const float* __restrict__ kbuf,
                                                   const float* __restrict__ vbuf,
                                                   const float* __restrict__ mbias) {
    __shared__ float Ks[LL][65];     // pitch 65 -> row-major reads by consecutive-row lanes conflict-free
    __shared__ float Vs[LL][65];
    __shared__ float qrow[4][64];
    __shared__ float prow[4][128];
    int tid = threadIdx.x, wv = tid >> 6, lane = tid & 63;
    int b = blockIdx.x >> 3, hh = blockIdx.x & 7;
    const float* kb = kbuf + (size_t)(b * LL) * DD + hh * DHD;
    const float* vb = vbuf + (size_t)(b * LL) * DD + hh * DHD;
    for (int idx = tid; idx < LL * DHD; idx += 256) {
        int l = idx >> 6, dd = idx & 63;
        Ks[l][dd] = kb[(size_t)l * DD + dd];
        Vs[l][dd] = vb[(size_t)l * DD + dd];
    }
    __syncthreads();
    float* qb = qbuf + (size_t)(b * LL) * DD + hh * DHD;
    int  j2   = (lane + 64 > 99) ? 99 : lane + 64;
    bool has2 = (lane < 36);
    for (int it = 0; it < 25; ++it) {
        int l = it * 4 + wv;                     // this wave's query row
        qrow[wv][lane] = qb[(size_t)l * DD + lane];
        __syncthreads();
        float s0 = 0.f, s1 = 0.f;
        #pragma unroll 8
        for (int dh = 0; dh < 64; ++dh) {
            float qd = qrow[wv][dh];
            s0 += qd * Ks[lane][dh];
            s1 += qd * Ks[j2][dh];
        }
        const float* mrow = mbias + l * LL;
        s0 = s0 * 0.125f + mrow[lane];
        s1 = has2 ? (s1 * 0.125f + mrow[lane + 64]) : -3.0e38f;
        float m = fmaxf(s0, s1);
        #pragma unroll
        for (int off = 32; off; off >>= 1) m = fmaxf(m, __shfl_xor(m, off, 64));
        float p0 = expf(s0 - m);
        float p1 = has2 ? expf(s1 - m) : 0.f;
        float sum = p0 + p1;
        #pragma unroll
        for (int off = 32; off; off >>= 1) sum += __shfl_xor(sum, off, 64);
        float inv = 1.f / sum;
        prow[wv][lane]      = p0 * inv;
        prow[wv][lane + 64] = p1 * inv;
        __syncthreads();
        float acc = 0.f;
        #pragma unroll 4
        for (int j = 0; j < LL; ++j) acc += prow[wv][j] * Vs[j][lane];
        qb[(size_t)l * DD + lane] = acc;   // overwrite own q row (already consumed)
        __syncthreads();
    }
}

// ------------------------------------------------- residual + layernorm (in place on h)
template<bool RES>
__global__ __launch_bounds__(256) void add_ln(float* __restrict__ h,
                                              const float* __restrict__ res,
                                              const float* __restrict__ sc,
                                              const float* __restrict__ bi) {
    int n = blockIdx.x, tid = threadIdx.x;
    size_t base = (size_t)n * DD;
    float x0 = h[base + tid], x1 = h[base + 256 + tid];
    if (RES) { x0 += res[base + tid]; x1 += res[base + 256 + tid]; }
    float s = x0 + x1, ss = x0 * x0 + x1 * x1;
    #pragma unroll
    for (int off = 32; off; off >>= 1) {
        s  += __shfl_xor(s, off, 64);
        ss += __shfl_xor(ss, off, 64);
    }
    __shared__ float rs[4], rss[4];
    int wv = tid >> 6, lane = tid & 63;
    if (lane == 0) { rs[wv] = s; rss[wv] = ss; }
    __syncthreads();
    s  = rs[0] + rs[1] + rs[2] + rs[3];
    ss = rss[0] + rss[1] + rss[2] + rss[3];
    float mean = s * (1.f / (float)DD);
    float var  = ss * (1.f / (float)DD) - mean * mean;
    float rstd = 1.f / sqrtf(var + 1e-5f);
    h[base + tid]       = (x0 - mean) * rstd * sc[tid]       + bi[tid];
    h[base + 256 + tid] = (x1 - mean) * rstd * sc[256 + tid] + bi[256 + tid];
}

// ------------------------------------------------- final projection D -> 38
__global__ __launch_bounds__(64) void proj_kernel(const float* __restrict__ hn,
                                                  const float* __restrict__ pw,
                                                  const float* __restrict__ pb,
                                                  float* __restrict__ out) {
    __shared__ float row[DD];
    int n = blockIdx.x, lane = threadIdx.x;
    const float4* src = (const float4*)(hn + (size_t)n * DD);
    ((float4*)row)[lane]      = src[lane];
    ((float4*)row)[64 + lane] = src[64 + lane];
    __syncthreads();
    if (lane < COUT) {
        const float* w = pw + (size_t)lane * DD;
        float acc = pb[lane];
        #pragma unroll 8
        for (int k = 0; k < DD; ++k) acc += row[k] * w[k];
        out[(size_t)n * COUT + lane] = acc;
    }
}

__global__ void sentinel_kernel(float* out, int n) {
    int i = blockIdx.x * 256 + threadIdx.x;
    if (i < n) out[i] = 1.0e4f;   // distinctive: signals ws_size shortage, not a math bug
}

extern "C" void kernel_launch(void* const* d_in, const int* in_sizes, int n_in,
                              void* d_out, int out_size, void* d_ws, size_t ws_size,
                              hipStream_t stream) {
    const float* x    = (const float*)d_in[0];
    const float* ew   = (const float*)d_in[1];
    const float* Wq   = (const float*)d_in[2];
    const float* bq   = (const float*)d_in[3];
    const float* Wk   = (const float*)d_in[4];
    const float* bk   = (const float*)d_in[5];
    const float* Wv   = (const float*)d_in[6];
    const float* bv   = (const float*)d_in[7];
    const float* Wo   = (const float*)d_in[8];
    const float* bo   = (const float*)d_in[9];
    const float* c1w  = (const float*)d_in[10];
    const float* c1b  = (const float*)d_in[11];
    const float* c2w  = (const float*)d_in[12];
    const float* c2b  = (const float*)d_in[13];
    const float* ln1s = (const float*)d_in[14];
    const float* ln1b = (const float*)d_in[15];
    const float* ln2s = (const float*)d_in[16];
    const float* ln2b = (const float*)d_in[17];
    const float* lnfs = (const float*)d_in[18];
    const float* lnfb = (const float*)d_in[19];
    const float* pw   = (const float*)d_in[20];
    const float* pb   = (const float*)d_in[21];
    const unsigned char* mraw = (const unsigned char*)d_in[22];

    const size_t NB = (size_t)NTOK * DD;                       // 13,107,200 floats
    const size_t need = (4 * NB + (size_t)LL * DD + (size_t)LL * LL) * sizeof(float);
    if (ws_size < need) {
        sentinel_kernel<<<(out_size + 255) / 256, 256, 0, stream>>>((float*)d_out, out_size);
        return;
    }
    float* ws = (float*)d_ws;
    float* h  = ws;
    float* bA = ws + NB;        // q  / ffn-mid
    float* bB = ws + 2 * NB;    // k  / o-proj tmp
    float* bC = ws + 3 * NB;    // v  / ffn-out tmp
    float* pe = ws + 4 * NB;
    float* mb = pe + LL * DD;

    pe_kernel<<<(LL * DD + 255) / 256, 256, 0, stream>>>(pe);
    expand_mask_kernel<<<(LL * LL + 255) / 256, 256, 0, stream>>>(mraw, mb);
    embed_kernel<<<NTOK / 8, 256, 0, stream>>>(x, ew, pe, h);

    dim3 gg(DD / 64, NTOK / 64);   // (8, 400)
    for (int l = 0; l < EE; ++l) {
        const size_t wo  = (size_t)l * DD * DD;
        const size_t bof = (size_t)l * DD;
        gemm_xwT<0><<<gg, 256, 0, stream>>>(h,  Wq + wo, bq + bof, bA, NTOK, DD, DD);
        gemm_xwT<0><<<gg, 256, 0, stream>>>(h,  Wk + wo, bk + bof, bB, NTOK, DD, DD);
        gemm_xwT<0><<<gg, 256, 0, stream>>>(h,  Wv + wo, bv + bof, bC, NTOK, DD, DD);
        attn_kernel<<<BB * HH, 256, 0, stream>>>(bA, bB, bC, mb);
        gemm_xwT<0><<<gg, 256, 0, stream>>>(bA, Wo + wo, bo + bof, bB, NTOK, DD, DD);
        add_ln<true><<<NTOK, 256, 0, stream>>>(h, bB, ln1s + bof, ln1b + bof);
        gemm_xwT<1><<<gg, 256, 0, stream>>>(h,  c1w + wo, c1b + bof, bA, NTOK, DFF, DD);
        gemm_xwT<0><<<gg, 256, 0, stream>>>(bA, c2w + wo, c2b + bof, bC, NTOK, DD, DFF);
        add_ln<true><<<NTOK, 256, 0, stream>>>(h, bC, ln2s + bof, ln2b + bof);
    }
    add_ln<false><<<NTOK, 256, 0, stream>>>(h, nullptr, lnfs, lnfb);
    proj_kernel<<<NTOK, 64, 0, stream>>>(h, pw, pb, (float*)d_out);
}

// Round 3
// 2138.328 us; speedup vs baseline: 2.4744x; 2.4744x over previous
//
#include <hip/hip_runtime.h>
#include <math.h>

#define BB   256
#define LL   100
#define CIN  38
#define COUT 38
#define DD   512
#define HH   8
#define EE   3
#define DFF  512
#define DHD  64
#define NTOK (BB*LL)   // 25600
#define WELEM (EE*DD*DD) // 786432 elements per weight family

typedef __attribute__((ext_vector_type(8))) short bf16x8;
typedef __attribute__((ext_vector_type(4))) float f32x4;

__device__ __forceinline__ unsigned short f2bf(float f) {
    unsigned int u = __float_as_uint(f);
    unsigned int r = (u + 0x7FFFu + ((u >> 16) & 1u)) >> 16;
    return (unsigned short)r;
}
__device__ __forceinline__ float bf2f(unsigned short s) {
    return __uint_as_float(((unsigned int)s) << 16);
}

__device__ __forceinline__ void gl2lds16(const unsigned short* g, unsigned short* l) {
    __builtin_amdgcn_global_load_lds(
        (const __attribute__((address_space(1))) void*)g,
        (__attribute__((address_space(3))) void*)l, 16, 0, 0);
}

// ---------------------------------------------------------------- PE table
__global__ __launch_bounds__(256) void pe_kernel(float* __restrict__ pe) {
    int idx = blockIdx.x * 256 + threadIdx.x;
    if (idx >= LL * DD) return;
    int l = idx / DD, d = idx % DD;
    float e = (float)(d & ~1) * (-9.210340371976184f / (float)DD);
    float ang = (float)l * expf(e);
    pe[idx] = (d & 1) ? cosf(ang) : sinf(ang);
}

// ------------------------------------------------- mask -> additive bias
__global__ void expand_mask_kernel(const unsigned char* __restrict__ mraw,
                                   float* __restrict__ mb) {
    int i = blockIdx.x * 256 + threadIdx.x;
    if (i >= LL * LL) return;
    unsigned char b0 = mraw[0], b1 = mraw[1], b2 = mraw[2], b3 = mraw[3];
    bool v;
    if (b0 == 1 && b1 == 1)                      v = mraw[i] != 0;
    else if (b0 == 1 && b1 == 0 && b2 == 0 && b3 == 0)
                                                 v = ((const int*)mraw)[i] != 0;
    else if (b0 == 0x80 && b1 == 0x3F)           v = ((const unsigned short*)mraw)[i] != 0;
    else if (b0 == 0 && b1 == 0x3C)              v = ((const unsigned short*)mraw)[i] != 0;
    else if (b0 == 0 && b1 == 0 && b2 == 0x80 && b3 == 0x3F)
                                                 v = ((const float*)mraw)[i] != 0.f;
    else                                         v = mraw[i] != 0;
    mb[i] = v ? 0.f : -1.0e30f;
}

// ------------------------------------------------- fp32 -> bf16 bulk convert
__global__ __launch_bounds__(256) void cvt_kernel(const float* __restrict__ in,
                                                  unsigned short* __restrict__ out,
                                                  int n4) {   // n/4
    int i = blockIdx.x * 256 + threadIdx.x;
    if (i >= n4) return;
    float4 f = ((const float4*)in)[i];
    unsigned short o0 = f2bf(f.x), o1 = f2bf(f.y), o2 = f2bf(f.z), o3 = f2bf(f.w);
    unsigned long long packed = (unsigned long long)o0 | ((unsigned long long)o1 << 16)
                              | ((unsigned long long)o2 << 32) | ((unsigned long long)o3 << 48);
    ((unsigned long long*)out)[i] = packed;
}

// ---------------------------------------------------------------- embed (h out: bf16)
__global__ __launch_bounds__(256) void embed_kernel(const float* __restrict__ x,
                                                    const float* __restrict__ ew,
                                                    const float* __restrict__ pe,
                                                    unsigned short* __restrict__ h) {
    __shared__ float xw[8][114];
    __shared__ int   ls[8];
    int tid = threadIdx.x;
    int n0  = blockIdx.x * 8;
    if (tid < 8) ls[tid] = (n0 + tid) % LL;
    for (int idx = tid; idx < 8 * 114; idx += 256) {
        int tk = idx / 114, p = idx % 114;
        int slot = p / 38, c = p % 38;
        int n = n0 + tk; int b = n / LL, l = n % LL;
        int lsrc = (slot == 0) ? (l + LL - 1) % LL : (slot == 1) ? l : (l + 1) % LL;
        xw[tk][slot * 38 + c] = x[(size_t)(b * LL + lsrc) * CIN + c];
    }
    __syncthreads();
    for (int d = tid; d < DD; d += 256) {
        const float* w = ew + (size_t)d * 114;
        float acc[8] = {0.f,0.f,0.f,0.f,0.f,0.f,0.f,0.f};
        for (int c = 0; c < 38; ++c) {
            float w0 = w[c*3+0], w1 = w[c*3+1], w2 = w[c*3+2];
            #pragma unroll
            for (int tk = 0; tk < 8; ++tk)
                acc[tk] += xw[tk][c]*w0 + xw[tk][38+c]*w1 + xw[tk][76+c]*w2;
        }
        #pragma unroll
        for (int tk = 0; tk < 8; ++tk)
            h[(size_t)(n0 + tk) * DD + d] = f2bf(acc[tk] + pe[ls[tk] * DD + d]);
    }
}

// ------------------------------------------------- bf16 MFMA GEMM: C[M,N] = A[M,K] @ W[N,K]^T + bias
// m97 structure: 128x128 tile, BK=32, 4 waves (2x2), 4x4 16x16x32 fragments/wave.
template<int EPI>
__global__ __launch_bounds__(256) void gemm_bf16(const unsigned short* __restrict__ A,
                                                 const unsigned short* __restrict__ W,
                                                 const float* __restrict__ bias,
                                                 unsigned short* __restrict__ C,
                                                 int M, int N, int K) {
    __shared__ unsigned short As[128 * 32];
    __shared__ unsigned short Bs[128 * 32];
    const int tid  = threadIdx.x;
    const int bn   = blockIdx.x, bm = blockIdx.y;
    const int w    = tid >> 6, lane = tid & 63;
    const int wr   = w >> 1,  wc   = w & 1;
    // staging: 256 threads x 16B -> 4KB per issue; tile is 8KB -> 2 issues per operand
    const int sRow = tid >> 2;              // 0..63
    const int sK   = (tid & 3) * 8;         // element offset within BK=32
    const unsigned short* Ag = A + (size_t)(bm * 128 + sRow) * K + sK;
    const unsigned short* Wg = W + (size_t)(bn * 128 + sRow) * K + sK;
    unsigned short* AsD = As + tid * 8;     // == base + lane*16B within each wave
    unsigned short* BsD = Bs + tid * 8;
    const int fr = lane & 15, fq = lane >> 4;
    const int fo = fq * 8;                  // k-offset of this lane's fragment

    f32x4 acc[4][4] = {};
    for (int k0 = 0; k0 < K; k0 += 32) {
        gl2lds16(Ag + k0, AsD);
        gl2lds16(Ag + k0 + (size_t)64 * K, AsD + 64 * 32);
        gl2lds16(Wg + k0, BsD);
        gl2lds16(Wg + k0 + (size_t)64 * K, BsD + 64 * 32);
        __syncthreads();
        bf16x8 af[4], bfv[4];
        #pragma unroll
        for (int m = 0; m < 4; ++m)
            af[m] = *(const bf16x8*)(As + (wr * 64 + m * 16 + fr) * 32 + fo);
        #pragma unroll
        for (int n = 0; n < 4; ++n)
            bfv[n] = *(const bf16x8*)(Bs + (wc * 64 + n * 16 + fr) * 32 + fo);
        #pragma unroll
        for (int m = 0; m < 4; ++m)
            #pragma unroll
            for (int n = 0; n < 4; ++n)
                acc[m][n] = __builtin_amdgcn_mfma_f32_16x16x32_bf16(af[m], bfv[n], acc[m][n], 0, 0, 0);
        __syncthreads();
    }
    #pragma unroll
    for (int n = 0; n < 4; ++n) {
        int col = bn * 128 + wc * 64 + n * 16 + fr;
        float bv = bias[col];
        #pragma unroll
        for (int m = 0; m < 4; ++m) {
            #pragma unroll
            for (int j = 0; j < 4; ++j) {
                int row = bm * 128 + wr * 64 + m * 16 + fq * 4 + j;
                float v = acc[m][n][j] + bv;
                if (EPI == 1)
                    v = 0.5f * v * (1.f + erff(v * 0.70710678118654752f));
                C[(size_t)row * N + col] = f2bf(v);
            }
        }
    }
}

// ------------------------------------------------- attention, one (b,h) per block (bf16 buffers)
// per-wave private qrow/prow -> NO in-loop barriers needed (only after K/V staging)
__global__ __launch_bounds__(256) void attn_kernel(unsigned short* __restrict__ qbuf,
                                                   const unsigned short* __restrict__ kbuf,
                                                   const unsigned short* __restrict__ vbuf,
                                                   const float* __restrict__ mbias) {
    __shared__ float Ks[LL][65];
    __shared__ float Vs[LL][65];
    __shared__ float qrow[4][64];
    __shared__ float prow[4][128];
    int tid = threadIdx.x, wv = tid >> 6, lane = tid & 63;
    int b = blockIdx.x >> 3, hh = blockIdx.x & 7;
    const unsigned short* kb = kbuf + (size_t)(b * LL) * DD + hh * DHD;
    const unsigned short* vb = vbuf + (size_t)(b * LL) * DD + hh * DHD;
    for (int idx = tid; idx < LL * DHD; idx += 256) {
        int l = idx >> 6, dd = idx & 63;
        Ks[l][dd] = bf2f(kb[(size_t)l * DD + dd]);
        Vs[l][dd] = bf2f(vb[(size_t)l * DD + dd]);
    }
    __syncthreads();
    unsigned short* qb = qbuf + (size_t)(b * LL) * DD + hh * DHD;
    int  j2   = (lane + 64 > 99) ? 99 : lane + 64;
    bool has2 = (lane < 36);
    for (int it = 0; it < 25; ++it) {
        int l = it * 4 + wv;
        qrow[wv][lane] = bf2f(qb[(size_t)l * DD + lane]);
        float s0 = 0.f, s1 = 0.f;
        #pragma unroll 8
        for (int dh = 0; dh < 64; ++dh) {
            float qd = qrow[wv][dh];
            s0 += qd * Ks[lane][dh];
            s1 += qd * Ks[j2][dh];
        }
        const float* mrow = mbias + l * LL;
        s0 = s0 * 0.125f + mrow[lane];
        s1 = has2 ? (s1 * 0.125f + mrow[lane + 64]) : -3.0e38f;
        float m = fmaxf(s0, s1);
        #pragma unroll
        for (int off = 32; off; off >>= 1) m = fmaxf(m, __shfl_xor(m, off, 64));
        float p0 = expf(s0 - m);
        float p1 = has2 ? expf(s1 - m) : 0.f;
        float sum = p0 + p1;
        #pragma unroll
        for (int off = 32; off; off >>= 1) sum += __shfl_xor(sum, off, 64);
        float inv = 1.f / sum;
        prow[wv][lane]      = p0 * inv;
        prow[wv][lane + 64] = p1 * inv;
        float acc = 0.f;
        #pragma unroll 4
        for (int j = 0; j < LL; ++j) acc += prow[wv][j] * Vs[j][lane];
        qb[(size_t)l * DD + lane] = f2bf(acc);
    }
}

// ------------------------------------------------- residual + layernorm (bf16 in/out)
template<bool RES>
__global__ __launch_bounds__(256) void add_ln(unsigned short* __restrict__ h,
                                              const unsigned short* __restrict__ res,
                                              const float* __restrict__ sc,
                                              const float* __restrict__ bi) {
    int n = blockIdx.x, tid = threadIdx.x;
    size_t base = (size_t)n * DD;
    float x0 = bf2f(h[base + tid]), x1 = bf2f(h[base + 256 + tid]);
    if (RES) { x0 += bf2f(res[base + tid]); x1 += bf2f(res[base + 256 + tid]); }
    float s = x0 + x1, ss = x0 * x0 + x1 * x1;
    #pragma unroll
    for (int off = 32; off; off >>= 1) {
        s  += __shfl_xor(s, off, 64);
        ss += __shfl_xor(ss, off, 64);
    }
    __shared__ float rs[4], rss[4];
    int wv = tid >> 6, lane = tid & 63;
    if (lane == 0) { rs[wv] = s; rss[wv] = ss; }
    __syncthreads();
    s  = rs[0] + rs[1] + rs[2] + rs[3];
    ss = rss[0] + rss[1] + rss[2] + rss[3];
    float mean = s * (1.f / (float)DD);
    float var  = ss * (1.f / (float)DD) - mean * mean;
    float rstd = 1.f / sqrtf(var + 1e-5f);
    h[base + tid]       = f2bf((x0 - mean) * rstd * sc[tid]       + bi[tid]);
    h[base + 256 + tid] = f2bf((x1 - mean) * rstd * sc[256 + tid] + bi[256 + tid]);
}

// ------------------------------------------------- final projection D -> 38 (fp32 out)
__global__ __launch_bounds__(64) void proj_kernel(const unsigned short* __restrict__ hn,
                                                  const float* __restrict__ pw,
                                                  const float* __restrict__ pb,
                                                  float* __restrict__ out) {
    __shared__ float row[DD];
    int n = blockIdx.x, lane = threadIdx.x;
    const unsigned int* src = (const unsigned int*)(hn + (size_t)n * DD);
    for (int i = lane; i < DD / 2; i += 64) {
        unsigned int u = src[i];
        row[i * 2]     = __uint_as_float(u << 16);
        row[i * 2 + 1] = __uint_as_float(u & 0xFFFF0000u);
    }
    __syncthreads();
    if (lane < COUT) {
        const float* w = pw + (size_t)lane * DD;
        float acc = pb[lane];
        #pragma unroll 8
        for (int k = 0; k < DD; ++k) acc += row[k] * w[k];
        out[(size_t)n * COUT + lane] = acc;
    }
}

__global__ void sentinel_kernel(float* out, int n) {
    int i = blockIdx.x * 256 + threadIdx.x;
    if (i < n) out[i] = 1.0e4f;
}

extern "C" void kernel_launch(void* const* d_in, const int* in_sizes, int n_in,
                              void* d_out, int out_size, void* d_ws, size_t ws_size,
                              hipStream_t stream) {
    const float* x    = (const float*)d_in[0];
    const float* ew   = (const float*)d_in[1];
    const float* Wq   = (const float*)d_in[2];
    const float* bq   = (const float*)d_in[3];
    const float* Wk   = (const float*)d_in[4];
    const float* bk   = (const float*)d_in[5];
    const float* Wv   = (const float*)d_in[6];
    const float* bv   = (const float*)d_in[7];
    const float* Wo   = (const float*)d_in[8];
    const float* bo   = (const float*)d_in[9];
    const float* c1w  = (const float*)d_in[10];
    const float* c1b  = (const float*)d_in[11];
    const float* c2w  = (const float*)d_in[12];
    const float* c2b  = (const float*)d_in[13];
    const float* ln1s = (const float*)d_in[14];
    const float* ln1b = (const float*)d_in[15];
    const float* ln2s = (const float*)d_in[16];
    const float* ln2b = (const float*)d_in[17];
    const float* lnfs = (const float*)d_in[18];
    const float* lnfb = (const float*)d_in[19];
    const float* pw   = (const float*)d_in[20];
    const float* pb   = (const float*)d_in[21];
    const unsigned char* mraw = (const unsigned char*)d_in[22];

    const size_t NB = (size_t)NTOK * DD;   // 13,107,200 elements
    const size_t need = (4 * NB + 6 * (size_t)WELEM) * 2
                      + ((size_t)LL * DD + (size_t)LL * LL) * 4;
    if (ws_size < need) {
        sentinel_kernel<<<(out_size + 255) / 256, 256, 0, stream>>>((float*)d_out, out_size);
        return;
    }
    unsigned short* h  = (unsigned short*)d_ws;
    unsigned short* bA = h  + NB;
    unsigned short* bB = bA + NB;
    unsigned short* bC = bB + NB;
    unsigned short* wq = bC + NB;
    unsigned short* wk = wq + WELEM;
    unsigned short* wv = wk + WELEM;
    unsigned short* wo = wv + WELEM;
    unsigned short* w1 = wo + WELEM;
    unsigned short* w2 = w1 + WELEM;
    float* pe = (float*)(w2 + WELEM);
    float* mb = pe + LL * DD;

    pe_kernel<<<(LL * DD + 255) / 256, 256, 0, stream>>>(pe);
    expand_mask_kernel<<<(LL * LL + 255) / 256, 256, 0, stream>>>(mraw, mb);
    const int cg = WELEM / 4 / 256;   // 768 blocks
    cvt_kernel<<<cg, 256, 0, stream>>>(Wq,  wq, WELEM / 4);
    cvt_kernel<<<cg, 256, 0, stream>>>(Wk,  wk, WELEM / 4);
    cvt_kernel<<<cg, 256, 0, stream>>>(Wv,  wv, WELEM / 4);
    cvt_kernel<<<cg, 256, 0, stream>>>(Wo,  wo, WELEM / 4);
    cvt_kernel<<<cg, 256, 0, stream>>>(c1w, w1, WELEM / 4);
    cvt_kernel<<<cg, 256, 0, stream>>>(c2w, w2, WELEM / 4);
    embed_kernel<<<NTOK / 8, 256, 0, stream>>>(x, ew, pe, h);

    dim3 gg(DD / 128, NTOK / 128);   // (4, 200)
    for (int l = 0; l < EE; ++l) {
        const size_t wofs = (size_t)l * DD * DD;
        const size_t bof  = (size_t)l * DD;
        gemm_bf16<0><<<gg, 256, 0, stream>>>(h,  wq + wofs, bq + bof, bA, NTOK, DD, DD);
        gemm_bf16<0><<<gg, 256, 0, stream>>>(h,  wk + wofs, bk + bof, bB, NTOK, DD, DD);
        gemm_bf16<0><<<gg, 256, 0, stream>>>(h,  wv + wofs, bv + bof, bC, NTOK, DD, DD);
        attn_kernel<<<BB * HH, 256, 0, stream>>>(bA, bB, bC, mb);
        gemm_bf16<0><<<gg, 256, 0, stream>>>(bA, wo + wofs, bo + bof, bB, NTOK, DD, DD);
        add_ln<true><<<NTOK, 256, 0, stream>>>(h, bB, ln1s + bof, ln1b + bof);
        gemm_bf16<1><<<gg, 256, 0, stream>>>(h,  w1 + wofs, c1b + bof, bA, NTOK, DFF, DD);
        gemm_bf16<0><<<gg, 256, 0, stream>>>(bA, w2 + wofs, c2b + bof, bC, NTOK, DD, DFF);
        add_ln<true><<<NTOK, 256, 0, stream>>>(h, bC, ln2s + bof, ln2b + bof);
    }
    add_ln<false><<<NTOK, 256, 0, stream>>>(h, nullptr, lnfs, lnfb);
    proj_kernel<<<NTOK, 64, 0, stream>>>(h, pw, pb, (float*)d_out);
}

// Round 5
// 1255.718 us; speedup vs baseline: 4.2135x; 1.7029x over previous
//
#include <hip/hip_runtime.h>
#include <math.h>

#define BB   256
#define LL   100
#define CIN  38
#define COUT 38
#define DD   512
#define HH   8
#define EE   3
#define DFF  512
#define DHD  64
#define NTOK (BB*LL)   // 25600
#define WELEM (EE*DD*DD) // 786432 elements per weight family

typedef __attribute__((ext_vector_type(8))) short bf16x8;
typedef __attribute__((ext_vector_type(4))) float f32x4;

__device__ __forceinline__ unsigned short f2bf(float f) {
    unsigned int u = __float_as_uint(f);
    unsigned int r = (u + 0x7FFFu + ((u >> 16) & 1u)) >> 16;
    return (unsigned short)r;
}
__device__ __forceinline__ float bf2f(unsigned short s) {
    return __uint_as_float(((unsigned int)s) << 16);
}

__device__ __forceinline__ void gl2lds16(const unsigned short* g, unsigned short* l) {
    __builtin_amdgcn_global_load_lds(
        (const __attribute__((address_space(1))) void*)g,
        (__attribute__((address_space(3))) void*)l, 16, 0, 0);
}

// ---------------------------------------------------------------- PE table
__global__ __launch_bounds__(256) void pe_kernel(float* __restrict__ pe) {
    int idx = blockIdx.x * 256 + threadIdx.x;
    if (idx >= LL * DD) return;
    int l = idx / DD, d = idx % DD;
    float e = (float)(d & ~1) * (-9.210340371976184f / (float)DD);
    float ang = (float)l * expf(e);
    pe[idx] = (d & 1) ? cosf(ang) : sinf(ang);
}

// ------------------------------------------------- mask -> additive bias
__global__ void expand_mask_kernel(const unsigned char* __restrict__ mraw,
                                   float* __restrict__ mb) {
    int i = blockIdx.x * 256 + threadIdx.x;
    if (i >= LL * LL) return;
    unsigned char b0 = mraw[0], b1 = mraw[1], b2 = mraw[2], b3 = mraw[3];
    bool v;
    if (b0 == 1 && b1 == 1)                      v = mraw[i] != 0;
    else if (b0 == 1 && b1 == 0 && b2 == 0 && b3 == 0)
                                                 v = ((const int*)mraw)[i] != 0;
    else if (b0 == 0x80 && b1 == 0x3F)           v = ((const unsigned short*)mraw)[i] != 0;
    else if (b0 == 0 && b1 == 0x3C)              v = ((const unsigned short*)mraw)[i] != 0;
    else if (b0 == 0 && b1 == 0 && b2 == 0x80 && b3 == 0x3F)
                                                 v = ((const float*)mraw)[i] != 0.f;
    else                                         v = mraw[i] != 0;
    mb[i] = v ? 0.f : -1.0e30f;
}

// ------------------------------------------------- fp32 -> bf16 bulk convert
__global__ __launch_bounds__(256) void cvt_kernel(const float* __restrict__ in,
                                                  unsigned short* __restrict__ out,
                                                  int n4) {   // n/4
    int i = blockIdx.x * 256 + threadIdx.x;
    if (i >= n4) return;
    float4 f = ((const float4*)in)[i];
    unsigned short o0 = f2bf(f.x), o1 = f2bf(f.y), o2 = f2bf(f.z), o3 = f2bf(f.w);
    unsigned long long packed = (unsigned long long)o0 | ((unsigned long long)o1 << 16)
                              | ((unsigned long long)o2 << 32) | ((unsigned long long)o3 << 48);
    ((unsigned long long*)out)[i] = packed;
}

// ---------------------------------------------------------------- embed (h out: bf16)
__global__ __launch_bounds__(256) void embed_kernel(const float* __restrict__ x,
                                                    const float* __restrict__ ew,
                                                    const float* __restrict__ pe,
                                                    unsigned short* __restrict__ h) {
    __shared__ float xw[8][114];
    __shared__ int   ls[8];
    int tid = threadIdx.x;
    int n0  = blockIdx.x * 8;
    if (tid < 8) ls[tid] = (n0 + tid) % LL;
    for (int idx = tid; idx < 8 * 114; idx += 256) {
        int tk = idx / 114, p = idx % 114;
        int slot = p / 38, c = p % 38;
        int n = n0 + tk; int b = n / LL, l = n % LL;
        int lsrc = (slot == 0) ? (l + LL - 1) % LL : (slot == 1) ? l : (l + 1) % LL;
        xw[tk][slot * 38 + c] = x[(size_t)(b * LL + lsrc) * CIN + c];
    }
    __syncthreads();
    for (int d = tid; d < DD; d += 256) {
        const float* w = ew + (size_t)d * 114;
        float acc[8] = {0.f,0.f,0.f,0.f,0.f,0.f,0.f,0.f};
        for (int c = 0; c < 38; ++c) {
            float w0 = w[c*3+0], w1 = w[c*3+1], w2 = w[c*3+2];
            #pragma unroll
            for (int tk = 0; tk < 8; ++tk)
                acc[tk] += xw[tk][c]*w0 + xw[tk][38+c]*w1 + xw[tk][76+c]*w2;
        }
        #pragma unroll
        for (int tk = 0; tk < 8; ++tk)
            h[(size_t)(n0 + tk) * DD + d] = f2bf(acc[tk] + pe[ls[tk] * DD + d]);
    }
}

// ------------------------------------------------- bf16 MFMA GEMM: C[M,N] = A[M,K] @ W[N,K]^T + bias
template<int EPI>
__global__ __launch_bounds__(256) void gemm_bf16(const unsigned short* __restrict__ A,
                                                 const unsigned short* __restrict__ W,
                                                 const float* __restrict__ bias,
                                                 unsigned short* __restrict__ C,
                                                 int M, int N, int K) {
    __shared__ unsigned short As[128 * 32];
    __shared__ unsigned short Bs[128 * 32];
    const int tid  = threadIdx.x;
    const int bn   = blockIdx.x, bm = blockIdx.y;
    const int w    = tid >> 6, lane = tid & 63;
    const int wr   = w >> 1,  wc   = w & 1;
    const int sRow = tid >> 2;
    const int sK   = (tid & 3) * 8;
    const unsigned short* Ag = A + (size_t)(bm * 128 + sRow) * K + sK;
    const unsigned short* Wg = W + (size_t)(bn * 128 + sRow) * K + sK;
    unsigned short* AsD = As + tid * 8;
    unsigned short* BsD = Bs + tid * 8;
    const int fr = lane & 15, fq = lane >> 4;
    const int fo = fq * 8;

    f32x4 acc[4][4] = {};
    for (int k0 = 0; k0 < K; k0 += 32) {
        gl2lds16(Ag + k0, AsD);
        gl2lds16(Ag + k0 + (size_t)64 * K, AsD + 64 * 32);
        gl2lds16(Wg + k0, BsD);
        gl2lds16(Wg + k0 + (size_t)64 * K, BsD + 64 * 32);
        __syncthreads();
        bf16x8 af[4], bfv[4];
        #pragma unroll
        for (int m = 0; m < 4; ++m)
            af[m] = *(const bf16x8*)(As + (wr * 64 + m * 16 + fr) * 32 + fo);
        #pragma unroll
        for (int n = 0; n < 4; ++n)
            bfv[n] = *(const bf16x8*)(Bs + (wc * 64 + n * 16 + fr) * 32 + fo);
        #pragma unroll
        for (int m = 0; m < 4; ++m)
            #pragma unroll
            for (int n = 0; n < 4; ++n)
                acc[m][n] = __builtin_amdgcn_mfma_f32_16x16x32_bf16(af[m], bfv[n], acc[m][n], 0, 0, 0);
        __syncthreads();
    }
    #pragma unroll
    for (int n = 0; n < 4; ++n) {
        int col = bn * 128 + wc * 64 + n * 16 + fr;
        float bv = bias[col];
        #pragma unroll
        for (int m = 0; m < 4; ++m) {
            #pragma unroll
            for (int j = 0; j < 4; ++j) {
                int row = bm * 128 + wr * 64 + m * 16 + fq * 4 + j;
                float v = acc[m][n][j] + bv;
                if (EPI == 1)
                    v = 0.5f * v * (1.f + erff(v * 0.70710678118654752f));
                C[(size_t)row * N + col] = f2bf(v);
            }
        }
    }
}

// ------------------------------------------------- MFMA attention, one (b,h) per block
// LDS: Qs[112][64] bf16 swz @0, Ks[112][64] bf16 swz @14336, Vt[64][128] bf16 swz @28672,
//      P[wave][16][128] bf16 swz @45056. All row-swizzled: byte ^= (row&7)<<4.
// 4 waves; wave w computes row-bands {w, w+4} of 7 (16 rows each, rows 100..111 discarded).
// After the single staging barrier, waves are fully independent (per-wave P buffers).
__global__ __launch_bounds__(256) void attn_mfma(unsigned short* __restrict__ qbuf,
                                                 const unsigned short* __restrict__ kbuf,
                                                 const unsigned short* __restrict__ vbuf,
                                                 const float* __restrict__ mbias) {
    __shared__ __align__(16) unsigned char lds[61440];
    const int QOFF = 0, KOFF = 14336, VOFF = 28672, POFF = 45056;
    const int tid = threadIdx.x, wv = tid >> 6, lane = tid & 63;
    const int fr = lane & 15, fq = lane >> 4;
    const int b = blockIdx.x >> 3, hh = blockIdx.x & 7;
    const unsigned short* qg = qbuf + (size_t)(b * LL) * DD + hh * DHD;
    const unsigned short* kg = kbuf + (size_t)(b * LL) * DD + hh * DHD;
    const unsigned short* vg = vbuf + (size_t)(b * LL) * DD + hh * DHD;

    // ---- stage Q, K (row-swizzled) and V transposed
    for (int idx = tid; idx < 800; idx += 256) {
        int s = idx >> 3, c = idx & 7;
        uint4 qv = *(const uint4*)(qg + (size_t)s * DD + c * 8);
        uint4 kv = *(const uint4*)(kg + (size_t)s * DD + c * 8);
        uint4 vv = *(const uint4*)(vg + (size_t)s * DD + c * 8);
        int sw = (s & 7) << 4;
        *(uint4*)(lds + QOFF + s * 128 + ((c * 16) ^ sw)) = qv;
        *(uint4*)(lds + KOFF + s * 128 + ((c * 16) ^ sw)) = kv;
        unsigned int vs[4] = {vv.x, vv.y, vv.z, vv.w};
        #pragma unroll
        for (int e = 0; e < 4; ++e) {
            int d0 = c * 8 + e * 2, d1 = d0 + 1;
            *(unsigned short*)(lds + VOFF + d0 * 256 + ((s * 2) ^ ((d0 & 7) << 4))) = (unsigned short)(vs[e] & 0xFFFFu);
            *(unsigned short*)(lds + VOFF + d1 * 256 + ((s * 2) ^ ((d1 & 7) << 4))) = (unsigned short)(vs[e] >> 16);
        }
    }
    // zero pad rows 100..111 of Qs/Ks (NaN-safety for stale LDS)
    for (int idx = tid; idx < 192; idx += 256) {
        int t = (idx >= 96), r = 100 + ((idx % 96) >> 3), c = idx & 7;
        *(uint4*)(lds + t * 14336 + r * 128 + ((c * 16) ^ ((r & 7) << 4))) = uint4{0u, 0u, 0u, 0u};
    }
    // zero pad cols 100..127 of Vt
    for (int idx = tid; idx < 896; idx += 256) {
        int d = idx / 14, s = 100 + 2 * (idx % 14);
        *(unsigned int*)(lds + VOFF + d * 256 + ((s * 2) ^ ((d & 7) << 4))) = 0u;
    }
    __syncthreads();

    unsigned short* qout = qbuf + (size_t)(b * LL) * DD + hh * DHD;
    const int pbase = POFF + wv * 4096;
    for (int bd = wv; bd < 7; bd += 4) {
        // ---- S = (Q K^T)*0.125 + mask : 7 col-tiles, K=64 in 2 mfma steps
        bf16x8 aq0, aq1;
        {
            int row = bd * 16 + fr, sw = (row & 7) << 4;
            aq0 = *(const bf16x8*)(lds + QOFF + row * 128 + ((fq * 16) ^ sw));
            aq1 = *(const bf16x8*)(lds + QOFF + row * 128 + ((64 + fq * 16) ^ sw));
        }
        f32x4 sv[7];
        #pragma unroll
        for (int ct = 0; ct < 7; ++ct) {
            int row = ct * 16 + fr, sw = (row & 7) << 4;
            bf16x8 bk0 = *(const bf16x8*)(lds + KOFF + row * 128 + ((fq * 16) ^ sw));
            bf16x8 bk1 = *(const bf16x8*)(lds + KOFF + row * 128 + ((64 + fq * 16) ^ sw));
            f32x4 a = {0.f, 0.f, 0.f, 0.f};
            a = __builtin_amdgcn_mfma_f32_16x16x32_bf16(aq0, bk0, a, 0, 0, 0);
            a = __builtin_amdgcn_mfma_f32_16x16x32_bf16(aq1, bk1, a, 0, 0, 0);
            sv[ct] = a;
        }
        const int rg0 = bd * 16 + fq * 4;
        #pragma unroll
        for (int ct = 0; ct < 7; ++ct) {
            int col = ct * 16 + fr;
            #pragma unroll
            for (int j = 0; j < 4; ++j) {
                int rg = rg0 + j;
                float bias = (rg < LL && col < LL) ? mbias[rg * LL + col] : -1.0e30f;
                sv[ct][j] = sv[ct][j] * 0.125f + bias;
            }
        }
        // ---- row softmax (reduce over 7 regs + 16-lane fr group)
        float inv[4];
        #pragma unroll
        for (int j = 0; j < 4; ++j) {
            float mx = sv[0][j];
            #pragma unroll
            for (int ct = 1; ct < 7; ++ct) mx = fmaxf(mx, sv[ct][j]);
            #pragma unroll
            for (int off = 8; off; off >>= 1) mx = fmaxf(mx, __shfl_xor(mx, off, 64));
            float sum = 0.f;
            #pragma unroll
            for (int ct = 0; ct < 7; ++ct) {
                float p = __expf(sv[ct][j] - mx);
                sv[ct][j] = p; sum += p;
            }
            #pragma unroll
            for (int off = 8; off; off >>= 1) sum += __shfl_xor(sum, off, 64);
            inv[j] = 1.f / sum;
        }
        // ---- P -> LDS (bf16, swizzled); cols 112..127 zeroed (pad k-tile)
        asm volatile("s_waitcnt lgkmcnt(0)" ::: "memory");   // WAR: prior band's P reads done
        #pragma unroll
        for (int j = 0; j < 4; ++j) {
            int pr = fq * 4 + j, sw = (pr & 7) << 4;
            #pragma unroll
            for (int ct = 0; ct < 7; ++ct)
                *(unsigned short*)(lds + pbase + pr * 256 + ((ct * 32 + fr * 2) ^ sw)) = f2bf(sv[ct][j] * inv[j]);
            *(unsigned short*)(lds + pbase + pr * 256 + ((224 + fr * 2) ^ sw)) = 0;
        }
        asm volatile("s_waitcnt lgkmcnt(0)" ::: "memory");   // RAW: P visible to whole wave
        // ---- O = P V : 4 dh col-tiles, K=128 in 4 mfma steps
        f32x4 oacc[4] = {};
        #pragma unroll
        for (int kt = 0; kt < 4; ++kt) {
            bf16x8 ap = *(const bf16x8*)(lds + pbase + fr * 256 + ((kt * 64 + fq * 16) ^ ((fr & 7) << 4)));
            #pragma unroll
            for (int n = 0; n < 4; ++n) {
                int d = n * 16 + fr, sw = (d & 7) << 4;
                bf16x8 bv = *(const bf16x8*)(lds + VOFF + d * 256 + ((kt * 64 + fq * 16) ^ sw));
                oacc[n] = __builtin_amdgcn_mfma_f32_16x16x32_bf16(ap, bv, oacc[n], 0, 0, 0);
            }
        }
        // ---- store O in place over the Q slice
        #pragma unroll
        for (int j = 0; j < 4; ++j) {
            int rg = rg0 + j;
            if (rg < LL) {
                #pragma unroll
                for (int n = 0; n < 4; ++n)
                    qout[(size_t)rg * DD + n * 16 + fr] = f2bf(oacc[n][j]);
            }
        }
    }
}

// ------------------------------------------------- residual + layernorm (bf16 in/out)
template<bool RES>
__global__ __launch_bounds__(256) void add_ln(unsigned short* __restrict__ h,
                                              const unsigned short* __restrict__ res,
                                              const float* __restrict__ sc,
                                              const float* __restrict__ bi) {
    int n = blockIdx.x, tid = threadIdx.x;
    size_t base = (size_t)n * DD;
    float x0 = bf2f(h[base + tid]), x1 = bf2f(h[base + 256 + tid]);
    if (RES) { x0 += bf2f(res[base + tid]); x1 += bf2f(res[base + 256 + tid]); }
    float s = x0 + x1, ss = x0 * x0 + x1 * x1;
    #pragma unroll
    for (int off = 32; off; off >>= 1) {
        s  += __shfl_xor(s, off, 64);
        ss += __shfl_xor(ss, off, 64);
    }
    __shared__ float rs[4], rss[4];
    int wv = tid >> 6, lane = tid & 63;
    if (lane == 0) { rs[wv] = s; rss[wv] = ss; }
    __syncthreads();
    s  = rs[0] + rs[1] + rs[2] + rs[3];
    ss = rss[0] + rss[1] + rss[2] + rss[3];
    float mean = s * (1.f / (float)DD);
    float var  = ss * (1.f / (float)DD) - mean * mean;
    float rstd = 1.f / sqrtf(var + 1e-5f);
    h[base + tid]       = f2bf((x0 - mean) * rstd * sc[tid]       + bi[tid]);
    h[base + 256 + tid] = f2bf((x1 - mean) * rstd * sc[256 + tid] + bi[256 + tid]);
}

// ------------------------------------------------- final projection D -> 38 (fp32 out)
__global__ __launch_bounds__(64) void proj_kernel(const unsigned short* __restrict__ hn,
                                                  const float* __restrict__ pw,
                                                  const float* __restrict__ pb,
                                                  float* __restrict__ out) {
    __shared__ float row[DD];
    int n = blockIdx.x, lane = threadIdx.x;
    const unsigned int* src = (const unsigned int*)(hn + (size_t)n * DD);
    for (int i = lane; i < DD / 2; i += 64) {
        unsigned int u = src[i];
        row[i * 2]     = __uint_as_float(u << 16);
        row[i * 2 + 1] = __uint_as_float(u & 0xFFFF0000u);
    }
    __syncthreads();
    if (lane < COUT) {
        const float* w = pw + (size_t)lane * DD;
        float acc = pb[lane];
        #pragma unroll 8
        for (int k = 0; k < DD; ++k) acc += row[k] * w[k];
        out[(size_t)n * COUT + lane] = acc;
    }
}

__global__ void sentinel_kernel(float* out, int n) {
    int i = blockIdx.x * 256 + threadIdx.x;
    if (i < n) out[i] = 1.0e4f;
}

extern "C" void kernel_launch(void* const* d_in, const int* in_sizes, int n_in,
                              void* d_out, int out_size, void* d_ws, size_t ws_size,
                              hipStream_t stream) {
    const float* x    = (const float*)d_in[0];
    const float* ew   = (const float*)d_in[1];
    const float* Wq   = (const float*)d_in[2];
    const float* bq   = (const float*)d_in[3];
    const float* Wk   = (const float*)d_in[4];
    const float* bk   = (const float*)d_in[5];
    const float* Wv   = (const float*)d_in[6];
    const float* bv   = (const float*)d_in[7];
    const float* Wo   = (const float*)d_in[8];
    const float* bo   = (const float*)d_in[9];
    const float* c1w  = (const float*)d_in[10];
    const float* c1b  = (const float*)d_in[11];
    const float* c2w  = (const float*)d_in[12];
    const float* c2b  = (const float*)d_in[13];
    const float* ln1s = (const float*)d_in[14];
    const float* ln1b = (const float*)d_in[15];
    const float* ln2s = (const float*)d_in[16];
    const float* ln2b = (const float*)d_in[17];
    const float* lnfs = (const float*)d_in[18];
    const float* lnfb = (const float*)d_in[19];
    const float* pw   = (const float*)d_in[20];
    const float* pb   = (const float*)d_in[21];
    const unsigned char* mraw = (const unsigned char*)d_in[22];

    const size_t NB = (size_t)NTOK * DD;
    const size_t need = (4 * NB + 6 * (size_t)WELEM) * 2
                      + ((size_t)LL * DD + (size_t)LL * LL) * 4;
    if (ws_size < need) {
        sentinel_kernel<<<(out_size + 255) / 256, 256, 0, stream>>>((float*)d_out, out_size);
        return;
    }
    unsigned short* h  = (unsigned short*)d_ws;
    unsigned short* bA = h  + NB;
    unsigned short* bB = bA + NB;
    unsigned short* bC = bB + NB;
    unsigned short* wq = bC + NB;
    unsigned short* wk = wq + WELEM;
    unsigned short* wvp = wk + WELEM;
    unsigned short* wo = wvp + WELEM;
    unsigned short* w1 = wo + WELEM;
    unsigned short* w2 = w1 + WELEM;
    float* pe = (float*)(w2 + WELEM);
    float* mb = pe + LL * DD;

    pe_kernel<<<(LL * DD + 255) / 256, 256, 0, stream>>>(pe);
    expand_mask_kernel<<<(LL * LL + 255) / 256, 256, 0, stream>>>(mraw, mb);
    const int cg = WELEM / 4 / 256;
    cvt_kernel<<<cg, 256, 0, stream>>>(Wq,  wq,  WELEM / 4);
    cvt_kernel<<<cg, 256, 0, stream>>>(Wk,  wk,  WELEM / 4);
    cvt_kernel<<<cg, 256, 0, stream>>>(Wv,  wvp, WELEM / 4);
    cvt_kernel<<<cg, 256, 0, stream>>>(Wo,  wo,  WELEM / 4);
    cvt_kernel<<<cg, 256, 0, stream>>>(c1w, w1,  WELEM / 4);
    cvt_kernel<<<cg, 256, 0, stream>>>(c2w, w2,  WELEM / 4);
    embed_kernel<<<NTOK / 8, 256, 0, stream>>>(x, ew, pe, h);

    dim3 gg(DD / 128, NTOK / 128);
    for (int l = 0; l < EE; ++l) {
        const size_t wofs = (size_t)l * DD * DD;
        const size_t bof  = (size_t)l * DD;
        gemm_bf16<0><<<gg, 256, 0, stream>>>(h,  wq + wofs,  bq + bof, bA, NTOK, DD, DD);
        gemm_bf16<0><<<gg, 256, 0, stream>>>(h,  wk + wofs,  bk + bof, bB, NTOK, DD, DD);
        gemm_bf16<0><<<gg, 256, 0, stream>>>(h,  wvp + wofs, bv + bof, bC, NTOK, DD, DD);
        attn_mfma<<<BB * HH, 256, 0, stream>>>(bA, bB, bC, mb);
        gemm_bf16<0><<<gg, 256, 0, stream>>>(bA, wo + wofs,  bo + bof, bB, NTOK, DD, DD);
        add_ln<true><<<NTOK, 256, 0, stream>>>(h, bB, ln1s + bof, ln1b + bof);
        gemm_bf16<1><<<gg, 256, 0, stream>>>(h,  w1 + wofs,  c1b + bof, bA, NTOK, DFF, DD);
        gemm_bf16<0><<<gg, 256, 0, stream>>>(bA, w2 + wofs,  c2b + bof, bC, NTOK, DD, DFF);
        add_ln<true><<<NTOK, 256, 0, stream>>>(h, bC, ln2s + bof, ln2b + bof);
    }
    add_ln<false><<<NTOK, 256, 0, stream>>>(h, nullptr, lnfs, lnfb);
    proj_kernel<<<NTOK, 64, 0, stream>>>(h, pw, pb, (float*)d_out);
}

// Round 6
// 1031.561 us; speedup vs baseline: 5.1291x; 1.2173x over previous
//
#include <hip/hip_runtime.h>
#include <math.h>

#define BB   256
#define LL   100
#define CIN  38
#define COUT 38
#define DD   512
#define HH   8
#define EE   3
#define DFF  512
#define DHD  64
#define NTOK (BB*LL)   // 25600
#define WELEM (EE*DD*DD) // 786432 elements per weight family

typedef __attribute__((ext_vector_type(8))) short bf16x8;
typedef __attribute__((ext_vector_type(4))) float f32x4;

__device__ __forceinline__ unsigned short f2bf(float f) {
    unsigned int u = __float_as_uint(f);
    unsigned int r = (u + 0x7FFFu + ((u >> 16) & 1u)) >> 16;
    return (unsigned short)r;
}
__device__ __forceinline__ float bf2f(unsigned short s) {
    return __uint_as_float(((unsigned int)s) << 16);
}

__device__ __forceinline__ void gl2lds16(const unsigned short* g, unsigned short* l) {
    __builtin_amdgcn_global_load_lds(
        (const __attribute__((address_space(1))) void*)g,
        (__attribute__((address_space(3))) void*)l, 16, 0, 0);
}

// ---------------------------------------------------------------- PE table
__global__ __launch_bounds__(256) void pe_kernel(float* __restrict__ pe) {
    int idx = blockIdx.x * 256 + threadIdx.x;
    if (idx >= LL * DD) return;
    int l = idx / DD, d = idx % DD;
    float e = (float)(d & ~1) * (-9.210340371976184f / (float)DD);
    float ang = (float)l * expf(e);
    pe[idx] = (d & 1) ? cosf(ang) : sinf(ang);
}

// ------------------------------------------------- mask -> additive bias
__global__ void expand_mask_kernel(const unsigned char* __restrict__ mraw,
                                   float* __restrict__ mb) {
    int i = blockIdx.x * 256 + threadIdx.x;
    if (i >= LL * LL) return;
    unsigned char b0 = mraw[0], b1 = mraw[1], b2 = mraw[2], b3 = mraw[3];
    bool v;
    if (b0 == 1 && b1 == 1)                      v = mraw[i] != 0;
    else if (b0 == 1 && b1 == 0 && b2 == 0 && b3 == 0)
                                                 v = ((const int*)mraw)[i] != 0;
    else if (b0 == 0x80 && b1 == 0x3F)           v = ((const unsigned short*)mraw)[i] != 0;
    else if (b0 == 0 && b1 == 0x3C)              v = ((const unsigned short*)mraw)[i] != 0;
    else if (b0 == 0 && b1 == 0 && b2 == 0x80 && b3 == 0x3F)
                                                 v = ((const float*)mraw)[i] != 0.f;
    else                                         v = mraw[i] != 0;
    mb[i] = v ? 0.f : -1.0e30f;
}

// ------------------------------------------------- fp32 -> bf16 bulk convert
__global__ __launch_bounds__(256) void cvt_kernel(const float* __restrict__ in,
                                                  unsigned short* __restrict__ out,
                                                  int n4) {   // n/4
    int i = blockIdx.x * 256 + threadIdx.x;
    if (i >= n4) return;
    float4 f = ((const float4*)in)[i];
    unsigned short o0 = f2bf(f.x), o1 = f2bf(f.y), o2 = f2bf(f.z), o3 = f2bf(f.w);
    unsigned long long packed = (unsigned long long)o0 | ((unsigned long long)o1 << 16)
                              | ((unsigned long long)o2 << 32) | ((unsigned long long)o3 << 48);
    ((unsigned long long*)out)[i] = packed;
}

// ------------------------------------------------- proj weights -> bf16, padded [48][512]
__global__ __launch_bounds__(256) void proj_cvt(const float* __restrict__ in,
                                                unsigned short* __restrict__ outp) {
    int i = blockIdx.x * 256 + threadIdx.x;   // over 48*512/4 = 6144 chunks
    if (i >= 48 * DD / 4) return;
    if (i < COUT * DD / 4) {                  // 4864 exact chunks of real data
        float4 f = ((const float4*)in)[i];
        unsigned short o0 = f2bf(f.x), o1 = f2bf(f.y), o2 = f2bf(f.z), o3 = f2bf(f.w);
        unsigned long long packed = (unsigned long long)o0 | ((unsigned long long)o1 << 16)
                                  | ((unsigned long long)o2 << 32) | ((unsigned long long)o3 << 48);
        ((unsigned long long*)outp)[i] = packed;
    } else {
        ((unsigned long long*)outp)[i] = 0ull; // pad rows 38..47
    }
}

// ---------------------------------------------------------------- embed (h out: bf16)
__global__ __launch_bounds__(256) void embed_kernel(const float* __restrict__ x,
                                                    const float* __restrict__ ew,
                                                    const float* __restrict__ pe,
                                                    unsigned short* __restrict__ h) {
    __shared__ float xw[8][114];
    __shared__ int   ls[8];
    int tid = threadIdx.x;
    int n0  = blockIdx.x * 8;
    if (tid < 8) ls[tid] = (n0 + tid) % LL;
    for (int idx = tid; idx < 8 * 114; idx += 256) {
        int tk = idx / 114, p = idx % 114;
        int slot = p / 38, c = p % 38;
        int n = n0 + tk; int b = n / LL, l = n % LL;
        int lsrc = (slot == 0) ? (l + LL - 1) % LL : (slot == 1) ? l : (l + 1) % LL;
        xw[tk][slot * 38 + c] = x[(size_t)(b * LL + lsrc) * CIN + c];
    }
    __syncthreads();
    for (int d = tid; d < DD; d += 256) {
        const float* w = ew + (size_t)d * 114;
        float acc[8] = {0.f,0.f,0.f,0.f,0.f,0.f,0.f,0.f};
        for (int c = 0; c < 38; ++c) {
            float w0 = w[c*3+0], w1 = w[c*3+1], w2 = w[c*3+2];
            #pragma unroll
            for (int tk = 0; tk < 8; ++tk)
                acc[tk] += xw[tk][c]*w0 + xw[tk][38+c]*w1 + xw[tk][76+c]*w2;
        }
        #pragma unroll
        for (int tk = 0; tk < 8; ++tk)
            h[(size_t)(n0 + tk) * DD + d] = f2bf(acc[tk] + pe[ls[tk] * DD + d]);
    }
}

// ------------------------------------------------- bf16 MFMA GEMM: C[M,N] = A[M,K] @ W[N,K]^T + bias
template<int EPI>
__global__ __launch_bounds__(256) void gemm_bf16(const unsigned short* __restrict__ A,
                                                 const unsigned short* __restrict__ W,
                                                 const float* __restrict__ bias,
                                                 unsigned short* __restrict__ C,
                                                 int M, int N, int K) {
    __shared__ unsigned short As[128 * 32];
    __shared__ unsigned short Bs[128 * 32];
    const int tid  = threadIdx.x;
    const int bn   = blockIdx.x, bm = blockIdx.y;
    const int w    = tid >> 6, lane = tid & 63;
    const int wr   = w >> 1,  wc   = w & 1;
    const int sRow = tid >> 2;
    const int sK   = (tid & 3) * 8;
    const unsigned short* Ag = A + (size_t)(bm * 128 + sRow) * K + sK;
    const unsigned short* Wg = W + (size_t)(bn * 128 + sRow) * K + sK;
    unsigned short* AsD = As + tid * 8;
    unsigned short* BsD = Bs + tid * 8;
    const int fr = lane & 15, fq = lane >> 4;
    const int fo = fq * 8;

    f32x4 acc[4][4] = {};
    for (int k0 = 0; k0 < K; k0 += 32) {
        gl2lds16(Ag + k0, AsD);
        gl2lds16(Ag + k0 + (size_t)64 * K, AsD + 64 * 32);
        gl2lds16(Wg + k0, BsD);
        gl2lds16(Wg + k0 + (size_t)64 * K, BsD + 64 * 32);
        __syncthreads();
        bf16x8 af[4], bfv[4];
        #pragma unroll
        for (int m = 0; m < 4; ++m)
            af[m] = *(const bf16x8*)(As + (wr * 64 + m * 16 + fr) * 32 + fo);
        #pragma unroll
        for (int n = 0; n < 4; ++n)
            bfv[n] = *(const bf16x8*)(Bs + (wc * 64 + n * 16 + fr) * 32 + fo);
        #pragma unroll
        for (int m = 0; m < 4; ++m)
            #pragma unroll
            for (int n = 0; n < 4; ++n)
                acc[m][n] = __builtin_amdgcn_mfma_f32_16x16x32_bf16(af[m], bfv[n], acc[m][n], 0, 0, 0);
        __syncthreads();
    }
    #pragma unroll
    for (int n = 0; n < 4; ++n) {
        int col = bn * 128 + wc * 64 + n * 16 + fr;
        float bv = bias[col];
        #pragma unroll
        for (int m = 0; m < 4; ++m) {
            #pragma unroll
            for (int j = 0; j < 4; ++j) {
                int row = bm * 128 + wr * 64 + m * 16 + fq * 4 + j;
                float v = acc[m][n][j] + bv;
                if (EPI == 1)
                    v = 0.5f * v * (1.f + erff(v * 0.70710678118654752f));
                C[(size_t)row * N + col] = f2bf(v);
            }
        }
    }
}

// ------------------------------------------------- MFMA attention, one (b,h) per block
// LDS: Qs[112][64] bf16 swz @0, Ks[112][64] bf16 swz @14336, Vt[64][128] bf16 swz @28672,
//      P[wave][16][128] bf16 swz @45056. All row-swizzled: byte ^= (row&7)<<4.
__global__ __launch_bounds__(256) void attn_mfma(unsigned short* __restrict__ qbuf,
                                                 const unsigned short* __restrict__ kbuf,
                                                 const unsigned short* __restrict__ vbuf,
                                                 const float* __restrict__ mbias) {
    __shared__ __align__(16) unsigned char lds[61440];
    const int QOFF = 0, KOFF = 14336, VOFF = 28672, POFF = 45056;
    const int tid = threadIdx.x, wv = tid >> 6, lane = tid & 63;
    const int fr = lane & 15, fq = lane >> 4;
    const int b = blockIdx.x >> 3, hh = blockIdx.x & 7;
    const unsigned short* qg = qbuf + (size_t)(b * LL) * DD + hh * DHD;
    const unsigned short* kg = kbuf + (size_t)(b * LL) * DD + hh * DHD;
    const unsigned short* vg = vbuf + (size_t)(b * LL) * DD + hh * DHD;

    for (int idx = tid; idx < 800; idx += 256) {
        int s = idx >> 3, c = idx & 7;
        uint4 qv = *(const uint4*)(qg + (size_t)s * DD + c * 8);
        uint4 kv = *(const uint4*)(kg + (size_t)s * DD + c * 8);
        uint4 vv = *(const uint4*)(vg + (size_t)s * DD + c * 8);
        int sw = (s & 7) << 4;
        *(uint4*)(lds + QOFF + s * 128 + ((c * 16) ^ sw)) = qv;
        *(uint4*)(lds + KOFF + s * 128 + ((c * 16) ^ sw)) = kv;
        unsigned int vs[4] = {vv.x, vv.y, vv.z, vv.w};
        #pragma unroll
        for (int e = 0; e < 4; ++e) {
            int d0 = c * 8 + e * 2, d1 = d0 + 1;
            *(unsigned short*)(lds + VOFF + d0 * 256 + ((s * 2) ^ ((d0 & 7) << 4))) = (unsigned short)(vs[e] & 0xFFFFu);
            *(unsigned short*)(lds + VOFF + d1 * 256 + ((s * 2) ^ ((d1 & 7) << 4))) = (unsigned short)(vs[e] >> 16);
        }
    }
    for (int idx = tid; idx < 192; idx += 256) {
        int t = (idx >= 96), r = 100 + ((idx % 96) >> 3), c = idx & 7;
        *(uint4*)(lds + t * 14336 + r * 128 + ((c * 16) ^ ((r & 7) << 4))) = uint4{0u, 0u, 0u, 0u};
    }
    for (int idx = tid; idx < 896; idx += 256) {
        int d = idx / 14, s = 100 + 2 * (idx % 14);
        *(unsigned int*)(lds + VOFF + d * 256 + ((s * 2) ^ ((d & 7) << 4))) = 0u;
    }
    __syncthreads();

    unsigned short* qout = qbuf + (size_t)(b * LL) * DD + hh * DHD;
    const int pbase = POFF + wv * 4096;
    for (int bd = wv; bd < 7; bd += 4) {
        bf16x8 aq0, aq1;
        {
            int row = bd * 16 + fr, sw = (row & 7) << 4;
            aq0 = *(const bf16x8*)(lds + QOFF + row * 128 + ((fq * 16) ^ sw));
            aq1 = *(const bf16x8*)(lds + QOFF + row * 128 + ((64 + fq * 16) ^ sw));
        }
        f32x4 sv[7];
        #pragma unroll
        for (int ct = 0; ct < 7; ++ct) {
            int row = ct * 16 + fr, sw = (row & 7) << 4;
            bf16x8 bk0 = *(const bf16x8*)(lds + KOFF + row * 128 + ((fq * 16) ^ sw));
            bf16x8 bk1 = *(const bf16x8*)(lds + KOFF + row * 128 + ((64 + fq * 16) ^ sw));
            f32x4 a = {0.f, 0.f, 0.f, 0.f};
            a = __builtin_amdgcn_mfma_f32_16x16x32_bf16(aq0, bk0, a, 0, 0, 0);
            a = __builtin_amdgcn_mfma_f32_16x16x32_bf16(aq1, bk1, a, 0, 0, 0);
            sv[ct] = a;
        }
        const int rg0 = bd * 16 + fq * 4;
        #pragma unroll
        for (int ct = 0; ct < 7; ++ct) {
            int col = ct * 16 + fr;
            #pragma unroll
            for (int j = 0; j < 4; ++j) {
                int rg = rg0 + j;
                float bias = (rg < LL && col < LL) ? mbias[rg * LL + col] : -1.0e30f;
                sv[ct][j] = sv[ct][j] * 0.125f + bias;
            }
        }
        float inv[4];
        #pragma unroll
        for (int j = 0; j < 4; ++j) {
            float mx = sv[0][j];
            #pragma unroll
            for (int ct = 1; ct < 7; ++ct) mx = fmaxf(mx, sv[ct][j]);
            #pragma unroll
            for (int off = 8; off; off >>= 1) mx = fmaxf(mx, __shfl_xor(mx, off, 64));
            float sum = 0.f;
            #pragma unroll
            for (int ct = 0; ct < 7; ++ct) {
                float p = __expf(sv[ct][j] - mx);
                sv[ct][j] = p; sum += p;
            }
            #pragma unroll
            for (int off = 8; off; off >>= 1) sum += __shfl_xor(sum, off, 64);
            inv[j] = 1.f / sum;
        }
        asm volatile("s_waitcnt lgkmcnt(0)" ::: "memory");
        #pragma unroll
        for (int j = 0; j < 4; ++j) {
            int pr = fq * 4 + j, sw = (pr & 7) << 4;
            #pragma unroll
            for (int ct = 0; ct < 7; ++ct)
                *(unsigned short*)(lds + pbase + pr * 256 + ((ct * 32 + fr * 2) ^ sw)) = f2bf(sv[ct][j] * inv[j]);
            *(unsigned short*)(lds + pbase + pr * 256 + ((224 + fr * 2) ^ sw)) = 0;
        }
        asm volatile("s_waitcnt lgkmcnt(0)" ::: "memory");
        f32x4 oacc[4] = {};
        #pragma unroll
        for (int kt = 0; kt < 4; ++kt) {
            bf16x8 ap = *(const bf16x8*)(lds + pbase + fr * 256 + ((kt * 64 + fq * 16) ^ ((fr & 7) << 4)));
            #pragma unroll
            for (int n = 0; n < 4; ++n) {
                int d = n * 16 + fr, sw = (d & 7) << 4;
                bf16x8 bv = *(const bf16x8*)(lds + VOFF + d * 256 + ((kt * 64 + fq * 16) ^ sw));
                oacc[n] = __builtin_amdgcn_mfma_f32_16x16x32_bf16(ap, bv, oacc[n], 0, 0, 0);
            }
        }
        #pragma unroll
        for (int j = 0; j < 4; ++j) {
            int rg = rg0 + j;
            if (rg < LL) {
                #pragma unroll
                for (int n = 0; n < 4; ++n)
                    qout[(size_t)rg * DD + n * 16 + fr] = f2bf(oacc[n][j]);
            }
        }
    }
}

// ------------------------------------------------- residual + layernorm (bf16 in/out)
template<bool RES>
__global__ __launch_bounds__(256) void add_ln(unsigned short* __restrict__ h,
                                              const unsigned short* __restrict__ res,
                                              const float* __restrict__ sc,
                                              const float* __restrict__ bi) {
    int n = blockIdx.x, tid = threadIdx.x;
    size_t base = (size_t)n * DD;
    float x0 = bf2f(h[base + tid]), x1 = bf2f(h[base + 256 + tid]);
    if (RES) { x0 += bf2f(res[base + tid]); x1 += bf2f(res[base + 256 + tid]); }
    float s = x0 + x1, ss = x0 * x0 + x1 * x1;
    #pragma unroll
    for (int off = 32; off; off >>= 1) {
        s  += __shfl_xor(s, off, 64);
        ss += __shfl_xor(ss, off, 64);
    }
    __shared__ float rs[4], rss[4];
    int wv = tid >> 6, lane = tid & 63;
    if (lane == 0) { rs[wv] = s; rss[wv] = ss; }
    __syncthreads();
    s  = rs[0] + rs[1] + rs[2] + rs[3];
    ss = rss[0] + rss[1] + rss[2] + rss[3];
    float mean = s * (1.f / (float)DD);
    float var  = ss * (1.f / (float)DD) - mean * mean;
    float rstd = 1.f / sqrtf(var + 1e-5f);
    h[base + tid]       = f2bf((x0 - mean) * rstd * sc[tid]       + bi[tid]);
    h[base + 256 + tid] = f2bf((x1 - mean) * rstd * sc[256 + tid] + bi[256 + tid]);
}

// ------------------------------------------------- final projection via MFMA
// M=25600, N=38 (padded 48), K=512. 400 blocks x 4 waves; wave owns 16 rows.
__global__ __launch_bounds__(256) void proj_mfma(const unsigned short* __restrict__ hn,
                                                 const unsigned short* __restrict__ pwb,
                                                 const float* __restrict__ pb,
                                                 float* __restrict__ out) {
    const int tid = threadIdx.x, wv = tid >> 6, lane = tid & 63;
    const int fr = lane & 15, fq = lane >> 4;
    const int row0 = blockIdx.x * 64 + wv * 16;
    const unsigned short* aRow = hn + (size_t)(row0 + fr) * DD + fq * 8;
    f32x4 acc[3] = {};
    #pragma unroll 4
    for (int kt = 0; kt < 16; ++kt) {
        bf16x8 af = *(const bf16x8*)(aRow + kt * 32);
        #pragma unroll
        for (int n = 0; n < 3; ++n) {
            bf16x8 bfv = *(const bf16x8*)(pwb + (size_t)(n * 16 + fr) * DD + kt * 32 + fq * 8);
            acc[n] = __builtin_amdgcn_mfma_f32_16x16x32_bf16(af, bfv, acc[n], 0, 0, 0);
        }
    }
    #pragma unroll
    for (int n = 0; n < 3; ++n) {
        int col = n * 16 + fr;
        if (col < COUT) {
            float bias = pb[col];
            #pragma unroll
            for (int j = 0; j < 4; ++j) {
                int r = row0 + fq * 4 + j;
                out[(size_t)r * COUT + col] = acc[n][j] + bias;
            }
        }
    }
}

__global__ void sentinel_kernel(float* out, int n) {
    int i = blockIdx.x * 256 + threadIdx.x;
    if (i < n) out[i] = 1.0e4f;
}

extern "C" void kernel_launch(void* const* d_in, const int* in_sizes, int n_in,
                              void* d_out, int out_size, void* d_ws, size_t ws_size,
                              hipStream_t stream) {
    const float* x    = (const float*)d_in[0];
    const float* ew   = (const float*)d_in[1];
    const float* Wq   = (const float*)d_in[2];
    const float* bq   = (const float*)d_in[3];
    const float* Wk   = (const float*)d_in[4];
    const float* bk   = (const float*)d_in[5];
    const float* Wv   = (const float*)d_in[6];
    const float* bv   = (const float*)d_in[7];
    const float* Wo   = (const float*)d_in[8];
    const float* bo   = (const float*)d_in[9];
    const float* c1w  = (const float*)d_in[10];
    const float* c1b  = (const float*)d_in[11];
    const float* c2w  = (const float*)d_in[12];
    const float* c2b  = (const float*)d_in[13];
    const float* ln1s = (const float*)d_in[14];
    const float* ln1b = (const float*)d_in[15];
    const float* ln2s = (const float*)d_in[16];
    const float* ln2b = (const float*)d_in[17];
    const float* lnfs = (const float*)d_in[18];
    const float* lnfb = (const float*)d_in[19];
    const float* pw   = (const float*)d_in[20];
    const float* pb   = (const float*)d_in[21];
    const unsigned char* mraw = (const unsigned char*)d_in[22];

    const size_t NB = (size_t)NTOK * DD;
    const size_t PWB = 48 * DD;   // padded proj weights (bf16 elems)
    const size_t need = (4 * NB + 6 * (size_t)WELEM + PWB) * 2
                      + ((size_t)LL * DD + (size_t)LL * LL) * 4;
    if (ws_size < need) {
        sentinel_kernel<<<(out_size + 255) / 256, 256, 0, stream>>>((float*)d_out, out_size);
        return;
    }
    unsigned short* h  = (unsigned short*)d_ws;
    unsigned short* bA = h  + NB;
    unsigned short* bB = bA + NB;
    unsigned short* bC = bB + NB;
    unsigned short* wq = bC + NB;
    unsigned short* wk = wq + WELEM;
    unsigned short* wvp = wk + WELEM;
    unsigned short* wo = wvp + WELEM;
    unsigned short* w1 = wo + WELEM;
    unsigned short* w2 = w1 + WELEM;
    unsigned short* pwb = w2 + WELEM;
    float* pe = (float*)(pwb + PWB);
    float* mb = pe + LL * DD;

    pe_kernel<<<(LL * DD + 255) / 256, 256, 0, stream>>>(pe);
    expand_mask_kernel<<<(LL * LL + 255) / 256, 256, 0, stream>>>(mraw, mb);
    const int cg = WELEM / 4 / 256;
    cvt_kernel<<<cg, 256, 0, stream>>>(Wq,  wq,  WELEM / 4);
    cvt_kernel<<<cg, 256, 0, stream>>>(Wk,  wk,  WELEM / 4);
    cvt_kernel<<<cg, 256, 0, stream>>>(Wv,  wvp, WELEM / 4);
    cvt_kernel<<<cg, 256, 0, stream>>>(Wo,  wo,  WELEM / 4);
    cvt_kernel<<<cg, 256, 0, stream>>>(c1w, w1,  WELEM / 4);
    cvt_kernel<<<cg, 256, 0, stream>>>(c2w, w2,  WELEM / 4);
    proj_cvt<<<(48 * DD / 4 + 255) / 256, 256, 0, stream>>>(pw, pwb);
    embed_kernel<<<NTOK / 8, 256, 0, stream>>>(x, ew, pe, h);

    dim3 gg(DD / 128, NTOK / 128);
    for (int l = 0; l < EE; ++l) {
        const size_t wofs = (size_t)l * DD * DD;
        const size_t bof  = (size_t)l * DD;
        gemm_bf16<0><<<gg, 256, 0, stream>>>(h,  wq + wofs,  bq + bof, bA, NTOK, DD, DD);
        gemm_bf16<0><<<gg, 256, 0, stream>>>(h,  wk + wofs,  bk + bof, bB, NTOK, DD, DD);
        gemm_bf16<0><<<gg, 256, 0, stream>>>(h,  wvp + wofs, bv + bof, bC, NTOK, DD, DD);
        attn_mfma<<<BB * HH, 256, 0, stream>>>(bA, bB, bC, mb);
        gemm_bf16<0><<<gg, 256, 0, stream>>>(bA, wo + wofs,  bo + bof, bB, NTOK, DD, DD);
        add_ln<true><<<NTOK, 256, 0, stream>>>(h, bB, ln1s + bof, ln1b + bof);
        gemm_bf16<1><<<gg, 256, 0, stream>>>(h,  w1 + wofs,  c1b + bof, bA, NTOK, DFF, DD);
        gemm_bf16<0><<<gg, 256, 0, stream>>>(bA, w2 + wofs,  c2b + bof, bC, NTOK, DD, DFF);
        add_ln<true><<<NTOK, 256, 0, stream>>>(h, bC, ln2s + bof, ln2b + bof);
    }
    add_ln<false><<<NTOK, 256, 0, stream>>>(h, nullptr, lnfs, lnfb);
    proj_mfma<<<NTOK / 64, 256, 0, stream>>>(h, pwb, pb, (float*)d_out);
}

// Round 7
// 833.441 us; speedup vs baseline: 6.3484x; 1.2377x over previous
//
#include <hip/hip_runtime.h>
#include <math.h>

#define BB   256
#define LL   100
#define CIN  38
#define COUT 38
#define DD   512
#define HH   8
#define EE   3
#define DFF  512
#define DHD  64
#define NTOK (BB*LL)     // 25600
#define WELEM (EE*DD*DD) // 786432 elements per weight family
#define QKVN 1536        // packed QKV width

typedef __attribute__((ext_vector_type(8))) short bf16x8;
typedef __attribute__((ext_vector_type(4))) float f32x4;

__device__ __forceinline__ unsigned short f2bf(float f) {
    unsigned int u = __float_as_uint(f);
    unsigned int r = (u + 0x7FFFu + ((u >> 16) & 1u)) >> 16;
    return (unsigned short)r;
}
__device__ __forceinline__ float bf2f(unsigned short s) {
    return __uint_as_float(((unsigned int)s) << 16);
}

__device__ __forceinline__ void gl2lds16(const unsigned short* g, unsigned short* l) {
    __builtin_amdgcn_global_load_lds(
        (const __attribute__((address_space(1))) void*)g,
        (__attribute__((address_space(3))) void*)l, 16, 0, 0);
}

// ---------------------------------------------------------------- PE table
__global__ __launch_bounds__(256) void pe_kernel(float* __restrict__ pe) {
    int idx = blockIdx.x * 256 + threadIdx.x;
    if (idx >= LL * DD) return;
    int l = idx / DD, d = idx % DD;
    float e = (float)(d & ~1) * (-9.210340371976184f / (float)DD);
    float ang = (float)l * expf(e);
    pe[idx] = (d & 1) ? cosf(ang) : sinf(ang);
}

// ------------------------------------------------- mask -> additive bias
__global__ void expand_mask_kernel(const unsigned char* __restrict__ mraw,
                                   float* __restrict__ mb) {
    int i = blockIdx.x * 256 + threadIdx.x;
    if (i >= LL * LL) return;
    unsigned char b0 = mraw[0], b1 = mraw[1], b2 = mraw[2], b3 = mraw[3];
    bool v;
    if (b0 == 1 && b1 == 1)                      v = mraw[i] != 0;
    else if (b0 == 1 && b1 == 0 && b2 == 0 && b3 == 0)
                                                 v = ((const int*)mraw)[i] != 0;
    else if (b0 == 0x80 && b1 == 0x3F)           v = ((const unsigned short*)mraw)[i] != 0;
    else if (b0 == 0 && b1 == 0x3C)              v = ((const unsigned short*)mraw)[i] != 0;
    else if (b0 == 0 && b1 == 0 && b2 == 0x80 && b3 == 0x3F)
                                                 v = ((const float*)mraw)[i] != 0.f;
    else                                         v = mraw[i] != 0;
    mb[i] = v ? 0.f : -1.0e30f;
}

// ------------------------------------------------- fp32 -> bf16 bulk convert
__global__ __launch_bounds__(256) void cvt_kernel(const float* __restrict__ in,
                                                  unsigned short* __restrict__ out,
                                                  int n4) {
    int i = blockIdx.x * 256 + threadIdx.x;
    if (i >= n4) return;
    float4 f = ((const float4*)in)[i];
    unsigned short o0 = f2bf(f.x), o1 = f2bf(f.y), o2 = f2bf(f.z), o3 = f2bf(f.w);
    unsigned long long packed = (unsigned long long)o0 | ((unsigned long long)o1 << 16)
                              | ((unsigned long long)o2 << 32) | ((unsigned long long)o3 << 48);
    ((unsigned long long*)out)[i] = packed;
}

// ------------------------------------------------- Wq/Wk/Wv -> packed [l][1536][512] bf16
__global__ __launch_bounds__(256) void cvt_pack(const float* __restrict__ in,
                                                unsigned short* __restrict__ out,
                                                int fam) {
    int i = blockIdx.x * 256 + threadIdx.x;      // over WELEM/4
    if (i >= WELEM / 4) return;
    int l = i >> 16;                              // / (DD*DD/4 = 65536)
    int j = i & 65535;
    float4 f = ((const float4*)in)[i];
    unsigned short o0 = f2bf(f.x), o1 = f2bf(f.y), o2 = f2bf(f.z), o3 = f2bf(f.w);
    unsigned long long packed = (unsigned long long)o0 | ((unsigned long long)o1 << 16)
                              | ((unsigned long long)o2 << 32) | ((unsigned long long)o3 << 48);
    ((unsigned long long*)out)[(size_t)l * (3 * 65536) + (size_t)fam * 65536 + j] = packed;
}

// ------------------------------------------------- bq/bk/bv -> packed [l][1536] fp32
__global__ __launch_bounds__(256) void pack_bias(const float* __restrict__ bq,
                                                 const float* __restrict__ bk,
                                                 const float* __restrict__ bv,
                                                 float* __restrict__ out) {
    int idx = blockIdx.x * 256 + threadIdx.x;    // EE*1536
    if (idx >= EE * QKVN) return;
    int l = idx / QKVN, r = idx % QKVN, f = r >> 9, d = r & 511;
    const float* src = (f == 0) ? bq : (f == 1) ? bk : bv;
    out[idx] = src[l * DD + d];
}

// ------------------------------------------------- proj weights -> bf16, padded [48][512]
__global__ __launch_bounds__(256) void proj_cvt(const float* __restrict__ in,
                                                unsigned short* __restrict__ outp) {
    int i = blockIdx.x * 256 + threadIdx.x;
    if (i >= 48 * DD / 4) return;
    if (i < COUT * DD / 4) {
        float4 f = ((const float4*)in)[i];
        unsigned short o0 = f2bf(f.x), o1 = f2bf(f.y), o2 = f2bf(f.z), o3 = f2bf(f.w);
        unsigned long long packed = (unsigned long long)o0 | ((unsigned long long)o1 << 16)
                                  | ((unsigned long long)o2 << 32) | ((unsigned long long)o3 << 48);
        ((unsigned long long*)outp)[i] = packed;
    } else {
        ((unsigned long long*)outp)[i] = 0ull;
    }
}

// ------------------------------------------------- emb_w [512][38*3] -> bf16 [512][128] (K-pad)
__global__ __launch_bounds__(256) void ewb_cvt(const float* __restrict__ ew,
                                               unsigned short* __restrict__ out) {
    int idx = blockIdx.x * 256 + threadIdx.x;    // 512*128
    if (idx >= DD * 128) return;
    int d = idx >> 7, k = idx & 127;
    out[idx] = (k < 114) ? f2bf(ew[d * 114 + k]) : (unsigned short)0;
}

// ------------------------------------------------- x -> ub[25600][128] bf16 (circular gather)
__global__ __launch_bounds__(256) void ub_build(const float* __restrict__ x,
                                                unsigned short* __restrict__ ub) {
    int idx = blockIdx.x * 256 + threadIdx.x;    // NTOK*128
    if (idx >= NTOK * 128) return;
    int n = idx >> 7, k = idx & 127;
    float v = 0.f;
    if (k < 114) {
        int c = k / 3, t = k - 3 * c;
        int l = n % LL, b = n / LL;
        int ls = l + t - 1;
        ls = (ls < 0) ? (LL - 1) : (ls >= LL ? ls - LL : ls);
        v = x[(size_t)(b * LL + ls) * CIN + c];
    }
    ub[idx] = f2bf(v);
}

// ------------------------------------------------- bf16 MFMA GEMM: C[M,N] = A[M,K] @ W[N,K]^T (+bias / +gelu / +pe)
// EPI: 0 = +bias, 1 = +bias+GELU, 2 = +pe[(row%LL)][col] (embed; bias unused)
template<int EPI>
__global__ __launch_bounds__(256) void gemm_bf16(const unsigned short* __restrict__ A,
                                                 const unsigned short* __restrict__ W,
                                                 const float* __restrict__ bias,
                                                 const float* __restrict__ pe2,
                                                 unsigned short* __restrict__ C,
                                                 int M, int N, int K, int lda, int ldc) {
    __shared__ unsigned short As[128 * 32];
    __shared__ unsigned short Bs[128 * 32];
    const int tid  = threadIdx.x;
    const int bn   = blockIdx.x, bm = blockIdx.y;
    const int w    = tid >> 6, lane = tid & 63;
    const int wr   = w >> 1,  wc   = w & 1;
    const int sRow = tid >> 2;
    const int sK   = (tid & 3) * 8;
    const unsigned short* Ag = A + (size_t)(bm * 128 + sRow) * lda + sK;
    const unsigned short* Wg = W + (size_t)(bn * 128 + sRow) * K + sK;
    unsigned short* AsD = As + tid * 8;
    unsigned short* BsD = Bs + tid * 8;
    const int fr = lane & 15, fq = lane >> 4;
    const int fo = fq * 8;

    f32x4 acc[4][4] = {};
    for (int k0 = 0; k0 < K; k0 += 32) {
        gl2lds16(Ag + k0, AsD);
        gl2lds16(Ag + k0 + (size_t)64 * lda, AsD + 64 * 32);
        gl2lds16(Wg + k0, BsD);
        gl2lds16(Wg + k0 + (size_t)64 * K, BsD + 64 * 32);
        __syncthreads();
        bf16x8 af[4], bfv[4];
        #pragma unroll
        for (int m = 0; m < 4; ++m)
            af[m] = *(const bf16x8*)(As + (wr * 64 + m * 16 + fr) * 32 + fo);
        #pragma unroll
        for (int n = 0; n < 4; ++n)
            bfv[n] = *(const bf16x8*)(Bs + (wc * 64 + n * 16 + fr) * 32 + fo);
        #pragma unroll
        for (int m = 0; m < 4; ++m)
            #pragma unroll
            for (int n = 0; n < 4; ++n)
                acc[m][n] = __builtin_amdgcn_mfma_f32_16x16x32_bf16(af[m], bfv[n], acc[m][n], 0, 0, 0);
        __syncthreads();
    }
    #pragma unroll
    for (int n = 0; n < 4; ++n) {
        int col = bn * 128 + wc * 64 + n * 16 + fr;
        float bv = (EPI != 2) ? bias[col] : 0.f;
        #pragma unroll
        for (int m = 0; m < 4; ++m) {
            #pragma unroll
            for (int j = 0; j < 4; ++j) {
                int row = bm * 128 + wr * 64 + m * 16 + fq * 4 + j;
                float v = acc[m][n][j] + bv;
                if (EPI == 1)
                    v = 0.5f * v * (1.f + erff(v * 0.70710678118654752f));
                if (EPI == 2)
                    v += pe2[(row % LL) * DD + col];
                C[(size_t)row * ldc + col] = f2bf(v);
            }
        }
    }
}

// ------------------------------------------------- MFMA attention on packed qkv[n][1536]
// q cols 0..511, k cols 512..1023, v cols 1024..1535; O overwrites the q slice.
// LDS: Qs[112][64] swz @0, Ks @14336, Vt[64][128] swz @28672, P[wave][16][128] @45056.
__global__ __launch_bounds__(256) void attn_mfma(unsigned short* __restrict__ qkv,
                                                 const float* __restrict__ mbias) {
    __shared__ __align__(16) unsigned char lds[61440];
    const int QOFF = 0, KOFF = 14336, VOFF = 28672, POFF = 45056;
    const int tid = threadIdx.x, wv = tid >> 6, lane = tid & 63;
    const int fr = lane & 15, fq = lane >> 4;
    const int b = blockIdx.x >> 3, hh = blockIdx.x & 7;
    unsigned short* qg = qkv + (size_t)(b * LL) * QKVN + hh * DHD;
    const unsigned short* kg = qg + 512;
    const unsigned short* vg = qg + 1024;

    for (int idx = tid; idx < 800; idx += 256) {
        int s = idx >> 3, c = idx & 7;
        uint4 qv = *(const uint4*)(qg + (size_t)s * QKVN + c * 8);
        uint4 kv = *(const uint4*)(kg + (size_t)s * QKVN + c * 8);
        uint4 vv = *(const uint4*)(vg + (size_t)s * QKVN + c * 8);
        int sw = (s & 7) << 4;
        *(uint4*)(lds + QOFF + s * 128 + ((c * 16) ^ sw)) = qv;
        *(uint4*)(lds + KOFF + s * 128 + ((c * 16) ^ sw)) = kv;
        unsigned int vs[4] = {vv.x, vv.y, vv.z, vv.w};
        #pragma unroll
        for (int e = 0; e < 4; ++e) {
            int d0 = c * 8 + e * 2, d1 = d0 + 1;
            *(unsigned short*)(lds + VOFF + d0 * 256 + ((s * 2) ^ ((d0 & 7) << 4))) = (unsigned short)(vs[e] & 0xFFFFu);
            *(unsigned short*)(lds + VOFF + d1 * 256 + ((s * 2) ^ ((d1 & 7) << 4))) = (unsigned short)(vs[e] >> 16);
        }
    }
    for (int idx = tid; idx < 192; idx += 256) {
        int t = (idx >= 96), r = 100 + ((idx % 96) >> 3), c = idx & 7;
        *(uint4*)(lds + t * 14336 + r * 128 + ((c * 16) ^ ((r & 7) << 4))) = uint4{0u, 0u, 0u, 0u};
    }
    for (int idx = tid; idx < 896; idx += 256) {
        int d = idx / 14, s = 100 + 2 * (idx % 14);
        *(unsigned int*)(lds + VOFF + d * 256 + ((s * 2) ^ ((d & 7) << 4))) = 0u;
    }
    __syncthreads();

    const int pbase = POFF + wv * 4096;
    for (int bd = wv; bd < 7; bd += 4) {
        bf16x8 aq0, aq1;
        {
            int row = bd * 16 + fr, sw = (row & 7) << 4;
            aq0 = *(const bf16x8*)(lds + QOFF + row * 128 + ((fq * 16) ^ sw));
            aq1 = *(const bf16x8*)(lds + QOFF + row * 128 + ((64 + fq * 16) ^ sw));
        }
        f32x4 sv[7];
        #pragma unroll
        for (int ct = 0; ct < 7; ++ct) {
            int row = ct * 16 + fr, sw = (row & 7) << 4;
            bf16x8 bk0 = *(const bf16x8*)(lds + KOFF + row * 128 + ((fq * 16) ^ sw));
            bf16x8 bk1 = *(const bf16x8*)(lds + KOFF + row * 128 + ((64 + fq * 16) ^ sw));
            f32x4 a = {0.f, 0.f, 0.f, 0.f};
            a = __builtin_amdgcn_mfma_f32_16x16x32_bf16(aq0, bk0, a, 0, 0, 0);
            a = __builtin_amdgcn_mfma_f32_16x16x32_bf16(aq1, bk1, a, 0, 0, 0);
            sv[ct] = a;
        }
        const int rg0 = bd * 16 + fq * 4;
        #pragma unroll
        for (int ct = 0; ct < 7; ++ct) {
            int col = ct * 16 + fr;
            #pragma unroll
            for (int j = 0; j < 4; ++j) {
                int rg = rg0 + j;
                float bias = (rg < LL && col < LL) ? mbias[rg * LL + col] : -1.0e30f;
                sv[ct][j] = sv[ct][j] * 0.125f + bias;
            }
        }
        float inv[4];
        #pragma unroll
        for (int j = 0; j < 4; ++j) {
            float mx = sv[0][j];
            #pragma unroll
            for (int ct = 1; ct < 7; ++ct) mx = fmaxf(mx, sv[ct][j]);
            #pragma unroll
            for (int off = 8; off; off >>= 1) mx = fmaxf(mx, __shfl_xor(mx, off, 64));
            float sum = 0.f;
            #pragma unroll
            for (int ct = 0; ct < 7; ++ct) {
                float p = __expf(sv[ct][j] - mx);
                sv[ct][j] = p; sum += p;
            }
            #pragma unroll
            for (int off = 8; off; off >>= 1) sum += __shfl_xor(sum, off, 64);
            inv[j] = 1.f / sum;
        }
        asm volatile("s_waitcnt lgkmcnt(0)" ::: "memory");
        #pragma unroll
        for (int j = 0; j < 4; ++j) {
            int pr = fq * 4 + j, sw = (pr & 7) << 4;
            #pragma unroll
            for (int ct = 0; ct < 7; ++ct)
                *(unsigned short*)(lds + pbase + pr * 256 + ((ct * 32 + fr * 2) ^ sw)) = f2bf(sv[ct][j] * inv[j]);
            *(unsigned short*)(lds + pbase + pr * 256 + ((224 + fr * 2) ^ sw)) = 0;
        }
        asm volatile("s_waitcnt lgkmcnt(0)" ::: "memory");
        f32x4 oacc[4] = {};
        #pragma unroll
        for (int kt = 0; kt < 4; ++kt) {
            bf16x8 ap = *(const bf16x8*)(lds + pbase + fr * 256 + ((kt * 64 + fq * 16) ^ ((fr & 7) << 4)));
            #pragma unroll
            for (int n = 0; n < 4; ++n) {
                int d = n * 16 + fr, sw = (d & 7) << 4;
                bf16x8 bv = *(const bf16x8*)(lds + VOFF + d * 256 + ((kt * 64 + fq * 16) ^ sw));
                oacc[n] = __builtin_amdgcn_mfma_f32_16x16x32_bf16(ap, bv, oacc[n], 0, 0, 0);
            }
        }
        #pragma unroll
        for (int j = 0; j < 4; ++j) {
            int rg = rg0 + j;
            if (rg < LL) {
                #pragma unroll
                for (int n = 0; n < 4; ++n)
                    qg[(size_t)rg * QKVN + n * 16 + fr] = f2bf(oacc[n][j]);
            }
        }
    }
}

// ------------------------------------------------- residual + layernorm (bf16 in/out)
template<bool RES>
__global__ __launch_bounds__(256) void add_ln(unsigned short* __restrict__ h,
                                              const unsigned short* __restrict__ res,
                                              const float* __restrict__ sc,
                                              const float* __restrict__ bi) {
    int n = blockIdx.x, tid = threadIdx.x;
    size_t base = (size_t)n * DD;
    float x0 = bf2f(h[base + tid]), x1 = bf2f(h[base + 256 + tid]);
    if (RES) { x0 += bf2f(res[base + tid]); x1 += bf2f(res[base + 256 + tid]); }
    float s = x0 + x1, ss = x0 * x0 + x1 * x1;
    #pragma unroll
    for (int off = 32; off; off >>= 1) {
        s  += __shfl_xor(s, off, 64);
        ss += __shfl_xor(ss, off, 64);
    }
    __shared__ float rs[4], rss[4];
    int wv = tid >> 6, lane = tid & 63;
    if (lane == 0) { rs[wv] = s; rss[wv] = ss; }
    __syncthreads();
    s  = rs[0] + rs[1] + rs[2] + rs[3];
    ss = rss[0] + rss[1] + rss[2] + rss[3];
    float mean = s * (1.f / (float)DD);
    float var  = ss * (1.f / (float)DD) - mean * mean;
    float rstd = 1.f / sqrtf(var + 1e-5f);
    h[base + tid]       = f2bf((x0 - mean) * rstd * sc[tid]       + bi[tid]);
    h[base + 256 + tid] = f2bf((x1 - mean) * rstd * sc[256 + tid] + bi[256 + tid]);
}

// ------------------------------------------------- final projection via MFMA
__global__ __launch_bounds__(256) void proj_mfma(const unsigned short* __restrict__ hn,
                                                 const unsigned short* __restrict__ pwb,
                                                 const float* __restrict__ pb,
                                                 float* __restrict__ out) {
    const int tid = threadIdx.x, wv = tid >> 6, lane = tid & 63;
    const int fr = lane & 15, fq = lane >> 4;
    const int row0 = blockIdx.x * 64 + wv * 16;
    const unsigned short* aRow = hn + (size_t)(row0 + fr) * DD + fq * 8;
    f32x4 acc[3] = {};
    #pragma unroll 4
    for (int kt = 0; kt < 16; ++kt) {
        bf16x8 af = *(const bf16x8*)(aRow + kt * 32);
        #pragma unroll
        for (int n = 0; n < 3; ++n) {
            bf16x8 bfv = *(const bf16x8*)(pwb + (size_t)(n * 16 + fr) * DD + kt * 32 + fq * 8);
            acc[n] = __builtin_amdgcn_mfma_f32_16x16x32_bf16(af, bfv, acc[n], 0, 0, 0);
        }
    }
    #pragma unroll
    for (int n = 0; n < 3; ++n) {
        int col = n * 16 + fr;
        if (col < COUT) {
            float bias = pb[col];
            #pragma unroll
            for (int j = 0; j < 4; ++j) {
                int r = row0 + fq * 4 + j;
                out[(size_t)r * COUT + col] = acc[n][j] + bias;
            }
        }
    }
}

__global__ void sentinel_kernel(float* out, int n) {
    int i = blockIdx.x * 256 + threadIdx.x;
    if (i < n) out[i] = 1.0e4f;
}

extern "C" void kernel_launch(void* const* d_in, const int* in_sizes, int n_in,
                              void* d_out, int out_size, void* d_ws, size_t ws_size,
                              hipStream_t stream) {
    const float* x    = (const float*)d_in[0];
    const float* ew   = (const float*)d_in[1];
    const float* Wq   = (const float*)d_in[2];
    const float* bq   = (const float*)d_in[3];
    const float* Wk   = (const float*)d_in[4];
    const float* bk   = (const float*)d_in[5];
    const float* Wv   = (const float*)d_in[6];
    const float* bv   = (const float*)d_in[7];
    const float* Wo   = (const float*)d_in[8];
    const float* bo   = (const float*)d_in[9];
    const float* c1w  = (const float*)d_in[10];
    const float* c1b  = (const float*)d_in[11];
    const float* c2w  = (const float*)d_in[12];
    const float* c2b  = (const float*)d_in[13];
    const float* ln1s = (const float*)d_in[14];
    const float* ln1b = (const float*)d_in[15];
    const float* ln2s = (const float*)d_in[16];
    const float* ln2b = (const float*)d_in[17];
    const float* lnfs = (const float*)d_in[18];
    const float* lnfb = (const float*)d_in[19];
    const float* pw   = (const float*)d_in[20];
    const float* pb   = (const float*)d_in[21];
    const unsigned char* mraw = (const unsigned char*)d_in[22];

    const size_t NB   = (size_t)NTOK * DD;       // 13,107,200
    const size_t PWB  = 48 * DD;
    const size_t EWB  = (size_t)DD * 128;
    const size_t UB   = (size_t)NTOK * 128;
    const size_t need = (5 * NB + 6 * (size_t)WELEM + PWB + EWB + UB) * 2
                      + ((size_t)EE * QKVN + (size_t)LL * DD + (size_t)LL * LL) * 4;
    if (ws_size < need) {
        sentinel_kernel<<<(out_size + 255) / 256, 256, 0, stream>>>((float*)d_out, out_size);
        return;
    }
    unsigned short* h    = (unsigned short*)d_ws;
    unsigned short* qkv  = h + NB;               // 3*NB (also FFN scratch)
    unsigned short* t1   = qkv + 3 * NB;
    unsigned short* wqkv = t1 + NB;              // 3*WELEM packed
    unsigned short* wo   = wqkv + 3 * WELEM;
    unsigned short* w1   = wo + WELEM;
    unsigned short* w2   = w1 + WELEM;
    unsigned short* pwb  = w2 + WELEM;
    unsigned short* ewb  = pwb + PWB;
    unsigned short* ub   = ewb + EWB;
    float* bqkv = (float*)(ub + UB);
    float* pe   = bqkv + EE * QKVN;
    float* mb   = pe + LL * DD;

    pe_kernel<<<(LL * DD + 255) / 256, 256, 0, stream>>>(pe);
    expand_mask_kernel<<<(LL * LL + 255) / 256, 256, 0, stream>>>(mraw, mb);
    const int cg = WELEM / 4 / 256;   // 768
    cvt_pack<<<cg, 256, 0, stream>>>(Wq, wqkv, 0);
    cvt_pack<<<cg, 256, 0, stream>>>(Wk, wqkv, 1);
    cvt_pack<<<cg, 256, 0, stream>>>(Wv, wqkv, 2);
    pack_bias<<<(EE * QKVN + 255) / 256, 256, 0, stream>>>(bq, bk, bv, bqkv);
    cvt_kernel<<<cg, 256, 0, stream>>>(Wo,  wo, WELEM / 4);
    cvt_kernel<<<cg, 256, 0, stream>>>(c1w, w1, WELEM / 4);
    cvt_kernel<<<cg, 256, 0, stream>>>(c2w, w2, WELEM / 4);
    proj_cvt<<<(48 * DD / 4 + 255) / 256, 256, 0, stream>>>(pw, pwb);
    ewb_cvt<<<(DD * 128 + 255) / 256, 256, 0, stream>>>(ew, ewb);
    ub_build<<<(NTOK * 128 + 255) / 256, 256, 0, stream>>>(x, ub);

    // embed as MFMA GEMM: h = ub @ ewb^T + PE
    dim3 gg(DD / 128, NTOK / 128);               // (4, 200)
    gemm_bf16<2><<<gg, 256, 0, stream>>>(ub, ewb, nullptr, pe, h, NTOK, DD, 128, 128, DD);

    dim3 g3(QKVN / 128, NTOK / 128);             // (12, 200)
    for (int l = 0; l < EE; ++l) {
        const size_t wofs = (size_t)l * DD * DD;
        const size_t bof  = (size_t)l * DD;
        gemm_bf16<0><<<g3, 256, 0, stream>>>(h, wqkv + (size_t)l * 3 * DD * DD, bqkv + l * QKVN,
                                             nullptr, qkv, NTOK, QKVN, DD, DD, QKVN);
        attn_mfma<<<BB * HH, 256, 0, stream>>>(qkv, mb);
        gemm_bf16<0><<<gg, 256, 0, stream>>>(qkv, wo + wofs, bo + bof, nullptr, t1,
                                             NTOK, DD, DD, QKVN, DD);
        add_ln<true><<<NTOK, 256, 0, stream>>>(h, t1, ln1s + bof, ln1b + bof);
        gemm_bf16<1><<<gg, 256, 0, stream>>>(h, w1 + wofs, c1b + bof, nullptr, qkv,
                                             NTOK, DFF, DD, DD, DFF);
        gemm_bf16<0><<<gg, 256, 0, stream>>>(qkv, w2 + wofs, c2b + bof, nullptr, t1,
                                             NTOK, DD, DFF, DFF, DD);
        add_ln<true><<<NTOK, 256, 0, stream>>>(h, t1, ln2s + bof, ln2b + bof);
    }
    add_ln<false><<<NTOK, 256, 0, stream>>>(h, nullptr, lnfs, lnfb);
    proj_mfma<<<NTOK / 64, 256, 0, stream>>>(h, pwb, pb, (float*)d_out);
}